// Round 7
// baseline (695.677 us; speedup 1.0000x reference)
//
#include <hip/hip_runtime.h>
#include <math.h>

#define IMH 480
#define IMW 640
#define HW (IMH*IMW)
#define KPT 512
#define DESC 256
#define CAP 32768
#define NMSR 3

// ---------------------------------------------------------------- MT19937
// Replicates np.random.RandomState(42).uniform(-8,8,(256,4)) -> round -> int.
__global__ void init_offsets_kernel(int* __restrict__ offs) {
  __shared__ unsigned int mt[624];
  __shared__ unsigned int old[624];
  __shared__ unsigned int tp[2496];   // 4 generations x 624 tempered draws
  const int tid = threadIdx.x;
  if (tid == 0) {
    unsigned int s = 42u;
    for (int i = 0; i < 624; ++i) { mt[i] = s; s = 1812433253u * (s ^ (s >> 30)) + (unsigned)i + 1u; }
  }
  __syncthreads();
  for (int g = 0; g < 4; ++g) {
    for (int k = tid; k < 624; k += 256) old[k] = mt[k];
    __syncthreads();
    for (int k = tid; k < 227; k += 256) {
      unsigned int y = (old[k] & 0x80000000u) | (old[k + 1] & 0x7fffffffu);
      mt[k] = old[k + 397] ^ (y >> 1) ^ ((y & 1u) ? 0x9908b0dfu : 0u);
    }
    __syncthreads();
    for (int k = 227 + tid; k < 454; k += 256) {
      unsigned int y = (old[k] & 0x80000000u) | (old[k + 1] & 0x7fffffffu);
      mt[k] = mt[k - 227] ^ (y >> 1) ^ ((y & 1u) ? 0x9908b0dfu : 0u);
    }
    __syncthreads();
    for (int k = 454 + tid; k < 623; k += 256) {
      unsigned int y = (old[k] & 0x80000000u) | (old[k + 1] & 0x7fffffffu);
      mt[k] = mt[k - 227] ^ (y >> 1) ^ ((y & 1u) ? 0x9908b0dfu : 0u);
    }
    __syncthreads();
    if (tid == 0) {
      unsigned int y = (old[623] & 0x80000000u) | (mt[0] & 0x7fffffffu);
      mt[623] = mt[396] ^ (y >> 1) ^ ((y & 1u) ? 0x9908b0dfu : 0u);
    }
    __syncthreads();
    for (int k = tid; k < 624; k += 256) {
      unsigned int y = mt[k];
      y ^= (y >> 11);
      y ^= (y << 7)  & 0x9d2c5680u;
      y ^= (y << 15) & 0xefc60000u;
      y ^= (y >> 18);
      tp[g * 624 + k] = y;
    }
    __syncthreads();
  }
  for (int i = tid; i < 1024; i += 256) {
    unsigned int a = tp[2 * i] >> 5, b = tp[2 * i + 1] >> 6;
    double r = ((double)a * 67108864.0 + (double)b) / 9007199254740992.0;
    offs[i] = (int)rint(-8.0 + 16.0 * r);
  }
}

#define SNB 16
__global__ void init_misc_kernel(int* __restrict__ counts, float* __restrict__ sel_val,
                                 int* __restrict__ sel_idx, float* __restrict__ a,
                                 float* __restrict__ b, int* __restrict__ flags,
                                 int* __restrict__ rank_arr) {
  int t = blockIdx.x * blockDim.x + threadIdx.x;
  if (t < 2) counts[t] = 0;
  if (t < SNB * 32) flags[t] = 0;
  if (t < 2 * KPT) { sel_val[t] = 0.f; sel_idx[t] = -1; }
  if (t < 513) { a[t] = 1.f; b[t] = 1.f; }   // b=exp(v)=1 initial; a overwritten phase 1
  for (int i = t; i < 2 * CAP; i += 16384) rank_arr[i] = 0;
}

// ---------------------------------------------------------------- detector (LDS-tiled)
#define DTW 64
#define DTH 16
__global__ void detector_kernel(const float* __restrict__ img0, const float* __restrict__ img1,
                                float* __restrict__ scores, float* __restrict__ smooth) {
  const int b = blockIdx.z;
  const int x0 = blockIdx.x * DTW;
  const int y0 = blockIdx.y * DTH;
  const float* __restrict__ img = b ? img1 : img0;
  __shared__ float tile[(DTH + 4) * (DTW + 4)];
  const int tid = threadIdx.x;
  for (int i = tid; i < (DTH + 4) * (DTW + 4); i += 256) {
    int ly = i / (DTW + 4), lx = i - ly * (DTW + 4);
    int gy = y0 + ly - 2, gx = x0 + lx - 2;
    tile[i] = (gy >= 0 && gy < IMH && gx >= 0 && gx < IMW) ? img[gy * IMW + gx] : 0.f;
  }
  __syncthreads();
  for (int i = tid; i < DTH * DTW; i += 256) {
    int ly = i / DTW, lx = i - ly * DTW;
    int y = y0 + ly, x = x0 + lx;
    float a[5][5];
    #pragma unroll
    for (int ii = 0; ii < 5; ++ii)
      #pragma unroll
      for (int jj = 0; jj < 5; ++jj)
        a[ii][jj] = tile[(ly + ii) * (DTW + 4) + lx + jj];
    float sm = 0.f;
    #pragma unroll
    for (int ii = 0; ii < 5; ++ii)
      #pragma unroll
      for (int jj = 0; jj < 5; ++jj) sm += a[ii][jj];
    smooth[b * HW + y * IMW + x] = sm * (1.f / 25.f);

    float sxx = 0.f, syy = 0.f, sxy = 0.f;
    #pragma unroll
    for (int cy = -1; cy <= 1; ++cy) {
      #pragma unroll
      for (int cx = -1; cx <= 1; ++cx) {
        int yy = y + cy, xx = x + cx;
        if (yy < 0 || yy >= IMH || xx < 0 || xx >= IMW) continue;
        int iu = cy + 2, iv = cx + 2;
        float ix = (a[iu - 1][iv + 1] - a[iu - 1][iv - 1])
                 + 2.f * (a[iu][iv + 1] - a[iu][iv - 1])
                 + (a[iu + 1][iv + 1] - a[iu + 1][iv - 1]);
        float iy = (a[iu + 1][iv - 1] + 2.f * a[iu + 1][iv] + a[iu + 1][iv + 1])
                 - (a[iu - 1][iv - 1] + 2.f * a[iu - 1][iv] + a[iu - 1][iv + 1]);
        sxx += ix * ix; syy += iy * iy; sxy += ix * iy;
      }
    }
    sxx *= (1.f / 9.f); syy *= (1.f / 9.f); sxy *= (1.f / 9.f);
    float half_tr = 0.5f * (sxx + syy);
    float hd = 0.5f * (sxx - syy);
    scores[b * HW + y * IMW + x] = half_tr - sqrtf(hd * hd + sxy * sxy + 1e-12f);
  }
}

// ---------------------------------------------------------------- NMS (separable 7x7 max, LDS-tiled) + compact
#define NTW 64
#define NTH 32
__global__ void nms_cand_kernel(const float* __restrict__ scores,
                                float* __restrict__ cand_val, int* __restrict__ cand_idx,
                                int* __restrict__ counts) {
  const int b = blockIdx.z;
  const int x0 = blockIdx.x * NTW;
  const int y0 = blockIdx.y * NTH;
  const float* __restrict__ sc = scores + b * HW;
  __shared__ float sm[(NTH + 6) * (NTW + 6)];
  __shared__ float hm[(NTH + 6) * NTW];
  const int tid = threadIdx.x;
  for (int i = tid; i < (NTH + 6) * (NTW + 6); i += 256) {
    int ly = i / (NTW + 6), lx = i - ly * (NTW + 6);
    int gy = y0 + ly - 3, gx = x0 + lx - 3;
    sm[i] = (gy >= 0 && gy < IMH && gx >= 0 && gx < IMW) ? sc[gy * IMW + gx] : -INFINITY;
  }
  __syncthreads();
  for (int i = tid; i < (NTH + 6) * NTW; i += 256) {
    int ly = i / NTW, lx = i - ly * NTW;
    const float* r = sm + ly * (NTW + 6) + lx;
    float m = r[0];
    #pragma unroll
    for (int d = 1; d < 7; ++d) m = fmaxf(m, r[d]);
    hm[i] = m;
  }
  __syncthreads();
  for (int i = tid; i < NTH * NTW; i += 256) {
    int ly = i / NTW, lx = i - ly * NTW;
    float s = sm[(ly + 3) * (NTW + 6) + lx + 3];
    if (s <= 0.f) continue;
    float m = hm[ly * NTW + lx];
    #pragma unroll
    for (int d = 1; d < 7; ++d) m = fmaxf(m, hm[(ly + d) * NTW + lx]);
    if (s >= m - 1e-7f) {
      int gy = y0 + ly, gx = x0 + lx;
      int slot = atomicAdd(&counts[b], 1);
      if (slot < CAP) {
        cand_val[b * CAP + slot] = s;
        cand_idx[b * CAP + slot] = gy * IMW + gx;
      }
    }
  }
}

// ---------------------------------------------------------------- top-512: 2D-tiled rank count
__global__ void rank_partial_kernel(const float* __restrict__ cand_val,
                                    const int* __restrict__ cand_idx,
                                    const int* __restrict__ counts,
                                    int* __restrict__ rank_arr) {
  int b = blockIdx.z;
  int n = counts[b]; if (n > CAP) n = CAP;
  if ((int)(blockIdx.x * 256) >= n || (int)(blockIdx.y * 256) >= n) return;
  const float* cv = cand_val + b * CAP;
  const int* ci = cand_idx + b * CAP;
  int i = blockIdx.x * 256 + threadIdx.x;
  int j = blockIdx.y * 256 + threadIdx.x;
  __shared__ unsigned long long sk[256];
  sk[threadIdx.x] = (j < n)
      ? (((unsigned long long)__float_as_uint(cv[j]) << 32) | (0xFFFFFFFFu - (unsigned)ci[j]))
      : 0ull;
  __syncthreads();
  if (i >= n) return;
  unsigned long long ki = ((unsigned long long)__float_as_uint(cv[i]) << 32)
                        | (0xFFFFFFFFu - (unsigned)ci[i]);
  int r = 0;
  #pragma unroll 8
  for (int t = 0; t < 256; ++t) r += (sk[t] > ki) ? 1 : 0;
  atomicAdd(&rank_arr[b * CAP + i], r);
}

__global__ void scatter_topk_kernel(const float* __restrict__ cand_val,
                                    const int* __restrict__ cand_idx,
                                    const int* __restrict__ counts,
                                    const int* __restrict__ rank_arr,
                                    float* __restrict__ sel_val, int* __restrict__ sel_idx) {
  int b = blockIdx.y;
  int n = counts[b]; if (n > CAP) n = CAP;
  int i = blockIdx.x * 256 + threadIdx.x;
  if (i >= n) return;
  int r = rank_arr[b * CAP + i];
  if (r < KPT) {
    sel_val[b * KPT + r] = cand_val[b * CAP + i];
    sel_idx[b * KPT + r] = cand_idx[b * CAP + i];
  }
}

// ---------------------------------------------------------------- kp out + BAD desc + L2 norm
__global__ void kp_desc_kernel(const float* __restrict__ sel_val, const int* __restrict__ sel_idx,
                               const float* __restrict__ smooth, const int* __restrict__ offs,
                               float* __restrict__ desc, float* __restrict__ a2_out,
                               float* __restrict__ out) {
  int blk = blockIdx.x;
  int b = blk >> 9;
  int k = blk & 511;
  int lane = threadIdx.x;
  float val = sel_val[b * KPT + k];
  int idx = sel_idx[b * KPT + k];
  bool valid = (val > 0.f) && (idx >= 0);
  int y = 0, x = 0;
  if (valid) { y = idx / IMW; x = idx - y * IMW; }
  const float* sm = smooth + b * HW;
  float d[4];
  #pragma unroll
  for (int t2 = 0; t2 < 4; ++t2) {
    int pp = (lane << 2) + t2;
    int oy1 = offs[4 * pp + 0], ox1 = offs[4 * pp + 1];
    int oy2 = offs[4 * pp + 2], ox2 = offs[4 * pp + 3];
    int ya = min(max(y + oy1, 0), IMH - 1), xa = min(max(x + ox1, 0), IMW - 1);
    int yb = min(max(y + oy2, 0), IMH - 1), xb = min(max(x + ox2, 0), IMW - 1);
    float v2 = sm[ya * IMW + xa] - sm[yb * IMW + xb];
    d[t2] = valid ? v2 : 0.f;
  }
  float ss = d[0] * d[0] + d[1] * d[1] + d[2] * d[2] + d[3] * d[3];
  #pragma unroll
  for (int off = 32; off; off >>= 1) ss += __shfl_down(ss, off);
  ss = __shfl(ss, 0);
  float scale = 1.f / (sqrtf(ss) + 1e-8f);
  float* dd = desc + (size_t)(b * KPT + k) * DESC;
  #pragma unroll
  for (int t2 = 0; t2 < 4; ++t2) dd[(lane << 2) + t2] = d[t2] * scale;
  if (lane == 0) {
    a2_out[b * KPT + k] = ss * scale * scale;
    float* kp = out + b * (2 * KPT) + k * 2;
    kp[0] = valid ? (float)y : -1.f;
    kp[1] = valid ? (float)x : -1.f;
  }
}

// ---------------------------------------------------------------- K = exp(sim) with dustbin (linear-domain Sinkhorn kernel matrix)
__global__ void similarity_kernel(const float* __restrict__ desc, const float* __restrict__ a2,
                                  float* __restrict__ K) {
  int t = blockIdx.x * blockDim.x + threadIdx.x;
  if (t >= 513 * 513) return;
  int k = t / 513;
  int l = t - k * 513;
  float z;
  if (k == KPT || l == KPT) {
    z = 1.0f;
  } else {
    const float* d1 = desc + (size_t)k * DESC;
    const float* d2 = desc + (size_t)(KPT + l) * DESC;
    float dot = 0.f;
    #pragma unroll 8
    for (int d = 0; d < DESC; ++d) dot += d1[d] * d2[d];
    float sq = a2[k] + a2[KPT + l] - 2.f * dot;
    sq = fmaxf(sq, 0.f);
    z = -sqrtf(sq + 1e-12f);
  }
  K[t] = expf(z);    // Z in [-2, 1] -> K in [0.135, 2.72], perfectly fp32-conditioned
}

// ---------------------------------------------------------------- fused sinkhorn, linear domain
// a = mu / (K b);  b = nu / (K^T a);  probs = K * a * b * 1024.
// Barrier: NO atomic RMW. Block g release-stores generation to its own
// cacheline-spaced flag; first wave polls all 16 flags with one
// lane-parallel relaxed load + ballot (R5's 16 contended fetch_adds cost
// ~8 us/barrier of cross-XCD cacheline ping-pong; stores to disjoint lines
// don't contend).
__device__ __forceinline__ void flag_barrier(int* __restrict__ flags, int gen, int g) {
  __syncthreads();   // all block stores complete (vmcnt drain) before publish
  if (threadIdx.x < 64) {
    if (threadIdx.x == 0)
      __hip_atomic_store(&flags[g * 32], gen, __ATOMIC_RELEASE, __HIP_MEMORY_SCOPE_AGENT);
    int slot = (threadIdx.x & (SNB - 1)) * 32;
    int guard = 0;
    while (true) {
      int f = __hip_atomic_load(&flags[slot], __ATOMIC_RELAXED, __HIP_MEMORY_SCOPE_AGENT);
      if (__ballot(f >= gen) == ~0ull) break;
      __builtin_amdgcn_s_sleep(1);
      if (++guard > (1 << 22)) break;   // hang insurance; never expected
    }
  }
  __syncthreads();
}

__global__ __launch_bounds__(1024) void sinkhorn_fused_kernel(
    const float* __restrict__ K, float* __restrict__ a, float* __restrict__ b,
    int* __restrict__ flags, float* __restrict__ out) {
  const int g = blockIdx.x;
  const int tid = threadIdx.x;
  const int wave = tid >> 6;
  const int lane = tid & 63;
  const int r0 = (g * 513) / SNB;
  const int r1 = ((g + 1) * 513) / SNB;
  __shared__ float sh[513];     // staged a or b (phase-alternating)
  const float MU = 1.0f / 1024.0f;    // exp(norm)
  const float MU_BIN = 0.5f;          // exp(log(512)+norm)
  int gen = 0;
  for (int it = 0; it < 20; ++it) {
    // ---- a-phase: a[r] = mu_r / sum_l K[r][l] * b[l]
    for (int i = tid; i < 513; i += 1024)
      sh[i] = __hip_atomic_load(&b[i], __ATOMIC_RELAXED, __HIP_MEMORY_SCOPE_AGENT);
    __syncthreads();
    for (int r = r0 + wave; r < r1; r += 16) {
      const float* kr = K + (size_t)r * 513;
      float s = 0.f;
      for (int idx = lane; idx < 513; idx += 64) s += kr[idx] * sh[idx];
      #pragma unroll
      for (int off = 32; off; off >>= 1) s += __shfl_xor(s, off);
      if (lane == 0)
        __hip_atomic_store(&a[r], ((r == KPT) ? MU_BIN : MU) / s,
                           __ATOMIC_RELEASE, __HIP_MEMORY_SCOPE_AGENT);
    }
    flag_barrier(flags, ++gen, g);
    // ---- b-phase: b[c] = nu_c / sum_k K[k][c] * a[k]
    for (int i = tid; i < 513; i += 1024)
      sh[i] = __hip_atomic_load(&a[i], __ATOMIC_RELAXED, __HIP_MEMORY_SCOPE_AGENT);
    __syncthreads();
    for (int c = r0 + wave; c < r1; c += 16) {
      float s = 0.f;
      for (int k = lane; k < 513; k += 64) s += K[(size_t)k * 513 + c] * sh[k];
      #pragma unroll
      for (int off = 32; off; off >>= 1) s += __shfl_xor(s, off);
      if (lane == 0)
        __hip_atomic_store(&b[c], ((c == KPT) ? MU_BIN : MU) / s,
                           __ATOMIC_RELEASE, __HIP_MEMORY_SCOPE_AGENT);
    }
    flag_barrier(flags, ++gen, g);
  }
  // ---- probs: out[r][l] = K[r][l] * a[r] * b[l] * 1024
  for (int i = tid; i < 513; i += 1024)
    sh[i] = __hip_atomic_load(&b[i], __ATOMIC_RELAXED, __HIP_MEMORY_SCOPE_AGENT);
  __syncthreads();
  for (int r = r0 + wave; r < r1; r += 16) {
    float ar = __hip_atomic_load(&a[r], __ATOMIC_RELAXED, __HIP_MEMORY_SCOPE_AGENT) * 1024.f;
    const float* kr = K + (size_t)r * 513;
    float* o = out + (size_t)r * 513;
    for (int idx = lane; idx < 513; idx += 64)
      o[idx] = kr[idx] * ar * sh[idx];
  }
}

// ---------------------------------------------------------------- launch
extern "C" void kernel_launch(void* const* d_in, const int* in_sizes, int n_in,
                              void* d_out, int out_size, void* d_ws, size_t ws_size,
                              hipStream_t stream) {
  const float* img1 = (const float*)d_in[0];
  const float* img2 = (const float*)d_in[1];
  float* out = (float*)d_out;

  char* p = (char*)d_ws;
  auto alloc = [&](size_t bytes) { char* r = p; p += (bytes + 255) & ~(size_t)255; return r; };
  int*   offs     = (int*)alloc(1024 * 4);
  int*   counts   = (int*)alloc(2 * 4);
  int*   flags    = (int*)alloc(SNB * 32 * 4);
  float* sel_val  = (float*)alloc(2 * KPT * 4);
  int*   sel_idx  = (int*)alloc(2 * KPT * 4);
  float* aa       = (float*)alloc(513 * 4);
  float* bb       = (float*)alloc(513 * 4);
  float* a2       = (float*)alloc(2 * KPT * 4);
  float* scores   = (float*)alloc((size_t)2 * HW * 4);
  float* smooth   = (float*)alloc((size_t)2 * HW * 4);
  float* cand_val = (float*)alloc((size_t)2 * CAP * 4);
  int*   cand_idx = (int*)alloc((size_t)2 * CAP * 4);
  int*   rank_arr = (int*)alloc((size_t)2 * CAP * 4);
  float* desc     = (float*)alloc((size_t)2 * KPT * DESC * 4);
  float* K        = (float*)alloc((size_t)513 * 513 * 4);

  init_offsets_kernel<<<1, 256, 0, stream>>>(offs);
  init_misc_kernel<<<64, 256, 0, stream>>>(counts, sel_val, sel_idx, aa, bb, flags, rank_arr);
  detector_kernel<<<dim3(IMW / DTW, IMH / DTH, 2), 256, 0, stream>>>(img1, img2, scores, smooth);
  nms_cand_kernel<<<dim3(IMW / NTW, IMH / NTH, 2), 256, 0, stream>>>(scores, cand_val, cand_idx, counts);
  rank_partial_kernel<<<dim3(CAP / 256, CAP / 256, 2), 256, 0, stream>>>(cand_val, cand_idx, counts, rank_arr);
  scatter_topk_kernel<<<dim3(CAP / 256, 2), 256, 0, stream>>>(cand_val, cand_idx, counts, rank_arr, sel_val, sel_idx);
  kp_desc_kernel<<<1024, 64, 0, stream>>>(sel_val, sel_idx, smooth, offs, desc, a2, out);
  similarity_kernel<<<(513 * 513 + 255) / 256, 256, 0, stream>>>(desc, a2, K);
  sinkhorn_fused_kernel<<<SNB, 1024, 0, stream>>>(K, aa, bb, flags, out + 2048);
}

// Round 8
// 393.021 us; speedup vs baseline: 1.7701x; 1.7701x over previous
//
#include <hip/hip_runtime.h>
#include <math.h>

#define IMH 480
#define IMW 640
#define HW (IMH*IMW)
#define KPT 512
#define DESC 256
#define CAP 32768
#define NMSR 3

// ---------------------------------------------------------------- MT19937
// Replicates np.random.RandomState(42).uniform(-8,8,(256,4)) -> round -> int.
__global__ void init_offsets_kernel(int* __restrict__ offs) {
  __shared__ unsigned int mt[624];
  __shared__ unsigned int old[624];
  __shared__ unsigned int tp[2496];   // 4 generations x 624 tempered draws
  const int tid = threadIdx.x;
  if (tid == 0) {
    unsigned int s = 42u;
    for (int i = 0; i < 624; ++i) { mt[i] = s; s = 1812433253u * (s ^ (s >> 30)) + (unsigned)i + 1u; }
  }
  __syncthreads();
  for (int g = 0; g < 4; ++g) {
    for (int k = tid; k < 624; k += 256) old[k] = mt[k];
    __syncthreads();
    for (int k = tid; k < 227; k += 256) {
      unsigned int y = (old[k] & 0x80000000u) | (old[k + 1] & 0x7fffffffu);
      mt[k] = old[k + 397] ^ (y >> 1) ^ ((y & 1u) ? 0x9908b0dfu : 0u);
    }
    __syncthreads();
    for (int k = 227 + tid; k < 454; k += 256) {
      unsigned int y = (old[k] & 0x80000000u) | (old[k + 1] & 0x7fffffffu);
      mt[k] = mt[k - 227] ^ (y >> 1) ^ ((y & 1u) ? 0x9908b0dfu : 0u);
    }
    __syncthreads();
    for (int k = 454 + tid; k < 623; k += 256) {
      unsigned int y = (old[k] & 0x80000000u) | (old[k + 1] & 0x7fffffffu);
      mt[k] = mt[k - 227] ^ (y >> 1) ^ ((y & 1u) ? 0x9908b0dfu : 0u);
    }
    __syncthreads();
    if (tid == 0) {
      unsigned int y = (old[623] & 0x80000000u) | (mt[0] & 0x7fffffffu);
      mt[623] = mt[396] ^ (y >> 1) ^ ((y & 1u) ? 0x9908b0dfu : 0u);
    }
    __syncthreads();
    for (int k = tid; k < 624; k += 256) {
      unsigned int y = mt[k];
      y ^= (y >> 11);
      y ^= (y << 7)  & 0x9d2c5680u;
      y ^= (y << 15) & 0xefc60000u;
      y ^= (y >> 18);
      tp[g * 624 + k] = y;
    }
    __syncthreads();
  }
  for (int i = tid; i < 1024; i += 256) {
    unsigned int a = tp[2 * i] >> 5, b = tp[2 * i + 1] >> 6;
    double r = ((double)a * 67108864.0 + (double)b) / 9007199254740992.0;
    offs[i] = (int)rint(-8.0 + 16.0 * r);
  }
}

__global__ void init_misc_kernel(int* __restrict__ counts, float* __restrict__ sel_val,
                                 int* __restrict__ sel_idx, float* __restrict__ a,
                                 float* __restrict__ b, int* __restrict__ rank_arr) {
  int t = blockIdx.x * blockDim.x + threadIdx.x;
  if (t < 2) counts[t] = 0;
  if (t < 2 * KPT) { sel_val[t] = 0.f; sel_idx[t] = -1; }
  if (t < 513) { a[t] = 1.f; b[t] = 1.f; }   // b=exp(v)=1 initial; a overwritten first phase
  for (int i = t; i < 2 * CAP; i += 16384) rank_arr[i] = 0;
}

// ---------------------------------------------------------------- detector (LDS-tiled)
#define DTW 64
#define DTH 16
__global__ void detector_kernel(const float* __restrict__ img0, const float* __restrict__ img1,
                                float* __restrict__ scores, float* __restrict__ smooth) {
  const int b = blockIdx.z;
  const int x0 = blockIdx.x * DTW;
  const int y0 = blockIdx.y * DTH;
  const float* __restrict__ img = b ? img1 : img0;
  __shared__ float tile[(DTH + 4) * (DTW + 4)];
  const int tid = threadIdx.x;
  for (int i = tid; i < (DTH + 4) * (DTW + 4); i += 256) {
    int ly = i / (DTW + 4), lx = i - ly * (DTW + 4);
    int gy = y0 + ly - 2, gx = x0 + lx - 2;
    tile[i] = (gy >= 0 && gy < IMH && gx >= 0 && gx < IMW) ? img[gy * IMW + gx] : 0.f;
  }
  __syncthreads();
  for (int i = tid; i < DTH * DTW; i += 256) {
    int ly = i / DTW, lx = i - ly * DTW;
    int y = y0 + ly, x = x0 + lx;
    float a[5][5];
    #pragma unroll
    for (int ii = 0; ii < 5; ++ii)
      #pragma unroll
      for (int jj = 0; jj < 5; ++jj)
        a[ii][jj] = tile[(ly + ii) * (DTW + 4) + lx + jj];
    float sm = 0.f;
    #pragma unroll
    for (int ii = 0; ii < 5; ++ii)
      #pragma unroll
      for (int jj = 0; jj < 5; ++jj) sm += a[ii][jj];
    smooth[b * HW + y * IMW + x] = sm * (1.f / 25.f);

    float sxx = 0.f, syy = 0.f, sxy = 0.f;
    #pragma unroll
    for (int cy = -1; cy <= 1; ++cy) {
      #pragma unroll
      for (int cx = -1; cx <= 1; ++cx) {
        int yy = y + cy, xx = x + cx;
        if (yy < 0 || yy >= IMH || xx < 0 || xx >= IMW) continue;
        int iu = cy + 2, iv = cx + 2;
        float ix = (a[iu - 1][iv + 1] - a[iu - 1][iv - 1])
                 + 2.f * (a[iu][iv + 1] - a[iu][iv - 1])
                 + (a[iu + 1][iv + 1] - a[iu + 1][iv - 1]);
        float iy = (a[iu + 1][iv - 1] + 2.f * a[iu + 1][iv] + a[iu + 1][iv + 1])
                 - (a[iu - 1][iv - 1] + 2.f * a[iu - 1][iv] + a[iu - 1][iv + 1]);
        sxx += ix * ix; syy += iy * iy; sxy += ix * iy;
      }
    }
    sxx *= (1.f / 9.f); syy *= (1.f / 9.f); sxy *= (1.f / 9.f);
    float half_tr = 0.5f * (sxx + syy);
    float hd = 0.5f * (sxx - syy);
    scores[b * HW + y * IMW + x] = half_tr - sqrtf(hd * hd + sxy * sxy + 1e-12f);
  }
}

// ---------------------------------------------------------------- NMS (separable 7x7 max, LDS-tiled) + compact
#define NTW 64
#define NTH 32
__global__ void nms_cand_kernel(const float* __restrict__ scores,
                                float* __restrict__ cand_val, int* __restrict__ cand_idx,
                                int* __restrict__ counts) {
  const int b = blockIdx.z;
  const int x0 = blockIdx.x * NTW;
  const int y0 = blockIdx.y * NTH;
  const float* __restrict__ sc = scores + b * HW;
  __shared__ float sm[(NTH + 6) * (NTW + 6)];
  __shared__ float hm[(NTH + 6) * NTW];
  const int tid = threadIdx.x;
  for (int i = tid; i < (NTH + 6) * (NTW + 6); i += 256) {
    int ly = i / (NTW + 6), lx = i - ly * (NTW + 6);
    int gy = y0 + ly - 3, gx = x0 + lx - 3;
    sm[i] = (gy >= 0 && gy < IMH && gx >= 0 && gx < IMW) ? sc[gy * IMW + gx] : -INFINITY;
  }
  __syncthreads();
  for (int i = tid; i < (NTH + 6) * NTW; i += 256) {
    int ly = i / NTW, lx = i - ly * NTW;
    const float* r = sm + ly * (NTW + 6) + lx;
    float m = r[0];
    #pragma unroll
    for (int d = 1; d < 7; ++d) m = fmaxf(m, r[d]);
    hm[i] = m;
  }
  __syncthreads();
  for (int i = tid; i < NTH * NTW; i += 256) {
    int ly = i / NTW, lx = i - ly * NTW;
    float s = sm[(ly + 3) * (NTW + 6) + lx + 3];
    if (s <= 0.f) continue;
    float m = hm[ly * NTW + lx];
    #pragma unroll
    for (int d = 1; d < 7; ++d) m = fmaxf(m, hm[(ly + d) * NTW + lx]);
    if (s >= m - 1e-7f) {
      int gy = y0 + ly, gx = x0 + lx;
      int slot = atomicAdd(&counts[b], 1);
      if (slot < CAP) {
        cand_val[b * CAP + slot] = s;
        cand_idx[b * CAP + slot] = gy * IMW + gx;
      }
    }
  }
}

// ---------------------------------------------------------------- top-512: 2D-tiled rank count
__global__ void rank_partial_kernel(const float* __restrict__ cand_val,
                                    const int* __restrict__ cand_idx,
                                    const int* __restrict__ counts,
                                    int* __restrict__ rank_arr) {
  int b = blockIdx.z;
  int n = counts[b]; if (n > CAP) n = CAP;
  if ((int)(blockIdx.x * 256) >= n || (int)(blockIdx.y * 256) >= n) return;
  const float* cv = cand_val + b * CAP;
  const int* ci = cand_idx + b * CAP;
  int i = blockIdx.x * 256 + threadIdx.x;
  int j = blockIdx.y * 256 + threadIdx.x;
  __shared__ unsigned long long sk[256];
  sk[threadIdx.x] = (j < n)
      ? (((unsigned long long)__float_as_uint(cv[j]) << 32) | (0xFFFFFFFFu - (unsigned)ci[j]))
      : 0ull;
  __syncthreads();
  if (i >= n) return;
  unsigned long long ki = ((unsigned long long)__float_as_uint(cv[i]) << 32)
                        | (0xFFFFFFFFu - (unsigned)ci[i]);
  int r = 0;
  #pragma unroll 8
  for (int t = 0; t < 256; ++t) r += (sk[t] > ki) ? 1 : 0;
  atomicAdd(&rank_arr[b * CAP + i], r);
}

__global__ void scatter_topk_kernel(const float* __restrict__ cand_val,
                                    const int* __restrict__ cand_idx,
                                    const int* __restrict__ counts,
                                    const int* __restrict__ rank_arr,
                                    float* __restrict__ sel_val, int* __restrict__ sel_idx) {
  int b = blockIdx.y;
  int n = counts[b]; if (n > CAP) n = CAP;
  int i = blockIdx.x * 256 + threadIdx.x;
  if (i >= n) return;
  int r = rank_arr[b * CAP + i];
  if (r < KPT) {
    sel_val[b * KPT + r] = cand_val[b * CAP + i];
    sel_idx[b * KPT + r] = cand_idx[b * CAP + i];
  }
}

// ---------------------------------------------------------------- kp out + BAD desc + L2 norm
__global__ void kp_desc_kernel(const float* __restrict__ sel_val, const int* __restrict__ sel_idx,
                               const float* __restrict__ smooth, const int* __restrict__ offs,
                               float* __restrict__ desc, float* __restrict__ a2_out,
                               float* __restrict__ out) {
  int blk = blockIdx.x;
  int b = blk >> 9;
  int k = blk & 511;
  int lane = threadIdx.x;
  float val = sel_val[b * KPT + k];
  int idx = sel_idx[b * KPT + k];
  bool valid = (val > 0.f) && (idx >= 0);
  int y = 0, x = 0;
  if (valid) { y = idx / IMW; x = idx - y * IMW; }
  const float* sm = smooth + b * HW;
  float d[4];
  #pragma unroll
  for (int t2 = 0; t2 < 4; ++t2) {
    int pp = (lane << 2) + t2;
    int oy1 = offs[4 * pp + 0], ox1 = offs[4 * pp + 1];
    int oy2 = offs[4 * pp + 2], ox2 = offs[4 * pp + 3];
    int ya = min(max(y + oy1, 0), IMH - 1), xa = min(max(x + ox1, 0), IMW - 1);
    int yb = min(max(y + oy2, 0), IMH - 1), xb = min(max(x + ox2, 0), IMW - 1);
    float v2 = sm[ya * IMW + xa] - sm[yb * IMW + xb];
    d[t2] = valid ? v2 : 0.f;
  }
  float ss = d[0] * d[0] + d[1] * d[1] + d[2] * d[2] + d[3] * d[3];
  #pragma unroll
  for (int off = 32; off; off >>= 1) ss += __shfl_down(ss, off);
  ss = __shfl(ss, 0);
  float scale = 1.f / (sqrtf(ss) + 1e-8f);
  float* dd = desc + (size_t)(b * KPT + k) * DESC;
  #pragma unroll
  for (int t2 = 0; t2 < 4; ++t2) dd[(lane << 2) + t2] = d[t2] * scale;
  if (lane == 0) {
    a2_out[b * KPT + k] = ss * scale * scale;
    float* kp = out + b * (2 * KPT) + k * 2;
    kp[0] = valid ? (float)y : -1.f;
    kp[1] = valid ? (float)x : -1.f;
  }
}

// ---------------------------------------------------------------- K = exp(sim), plus K^T for coalesced column phase
__global__ void similarity_kernel(const float* __restrict__ desc, const float* __restrict__ a2,
                                  float* __restrict__ K, float* __restrict__ Kt) {
  int t = blockIdx.x * blockDim.x + threadIdx.x;
  if (t >= 513 * 513) return;
  int k = t / 513;
  int l = t - k * 513;
  float z;
  if (k == KPT || l == KPT) {
    z = 1.0f;
  } else {
    const float* d1 = desc + (size_t)k * DESC;
    const float* d2 = desc + (size_t)(KPT + l) * DESC;
    float dot = 0.f;
    #pragma unroll 8
    for (int d = 0; d < DESC; ++d) dot += d1[d] * d2[d];
    float sq = a2[k] + a2[KPT + l] - 2.f * dot;
    sq = fmaxf(sq, 0.f);
    z = -sqrtf(sq + 1e-12f);
  }
  float e = expf(z);        // Z in [-2,1] -> K in [0.135, 2.72], fp32-safe
  K[t] = e;
  Kt[(size_t)l * 513 + k] = e;
}

// ---------------------------------------------------------------- sinkhorn, linear domain, multi-dispatch
// a = mu / (K b);  b = nu / (K^T a);  probs = K * a * b * 1024.
// Dispatch boundary IS the grid barrier (~2 us, graph-amortized) — every
// hand-rolled cross-XCD barrier measured 8-12 us/sync (R4/R5/R6).
__global__ void matvec_div_kernel(const float* __restrict__ M, const float* __restrict__ x,
                                  float* __restrict__ y) {
  const int r = blockIdx.x;          // 0..512
  const int lane = threadIdx.x;      // one wave
  const float* row = M + (size_t)r * 513;
  float s = 0.f;
  for (int i = lane; i < 513; i += 64) s += row[i] * x[i];
  #pragma unroll
  for (int off = 32; off; off >>= 1) s += __shfl_xor(s, off);
  if (lane == 0) {
    const float mu = (r == KPT) ? 0.5f : (1.0f / 1024.0f);
    y[r] = mu / s;
  }
}

__global__ void probs_kernel(const float* __restrict__ K, const float* __restrict__ a,
                             const float* __restrict__ b, float* __restrict__ out) {
  int t = blockIdx.x * blockDim.x + threadIdx.x;
  if (t >= 513 * 513) return;
  int k = t / 513;
  int l = t - k * 513;
  out[t] = K[t] * (a[k] * 1024.f) * b[l];
}

// ---------------------------------------------------------------- launch
extern "C" void kernel_launch(void* const* d_in, const int* in_sizes, int n_in,
                              void* d_out, int out_size, void* d_ws, size_t ws_size,
                              hipStream_t stream) {
  const float* img1 = (const float*)d_in[0];
  const float* img2 = (const float*)d_in[1];
  float* out = (float*)d_out;

  char* p = (char*)d_ws;
  auto alloc = [&](size_t bytes) { char* r = p; p += (bytes + 255) & ~(size_t)255; return r; };
  int*   offs     = (int*)alloc(1024 * 4);
  int*   counts   = (int*)alloc(2 * 4);
  float* sel_val  = (float*)alloc(2 * KPT * 4);
  int*   sel_idx  = (int*)alloc(2 * KPT * 4);
  float* aa       = (float*)alloc(513 * 4);
  float* bb       = (float*)alloc(513 * 4);
  float* a2       = (float*)alloc(2 * KPT * 4);
  float* scores   = (float*)alloc((size_t)2 * HW * 4);
  float* smooth   = (float*)alloc((size_t)2 * HW * 4);
  float* cand_val = (float*)alloc((size_t)2 * CAP * 4);
  int*   cand_idx = (int*)alloc((size_t)2 * CAP * 4);
  int*   rank_arr = (int*)alloc((size_t)2 * CAP * 4);
  float* desc     = (float*)alloc((size_t)2 * KPT * DESC * 4);
  float* K        = (float*)alloc((size_t)513 * 513 * 4);
  float* Kt       = (float*)alloc((size_t)513 * 513 * 4);

  init_offsets_kernel<<<1, 256, 0, stream>>>(offs);
  init_misc_kernel<<<64, 256, 0, stream>>>(counts, sel_val, sel_idx, aa, bb, rank_arr);
  detector_kernel<<<dim3(IMW / DTW, IMH / DTH, 2), 256, 0, stream>>>(img1, img2, scores, smooth);
  nms_cand_kernel<<<dim3(IMW / NTW, IMH / NTH, 2), 256, 0, stream>>>(scores, cand_val, cand_idx, counts);
  rank_partial_kernel<<<dim3(CAP / 256, CAP / 256, 2), 256, 0, stream>>>(cand_val, cand_idx, counts, rank_arr);
  scatter_topk_kernel<<<dim3(CAP / 256, 2), 256, 0, stream>>>(cand_val, cand_idx, counts, rank_arr, sel_val, sel_idx);
  kp_desc_kernel<<<1024, 64, 0, stream>>>(sel_val, sel_idx, smooth, offs, desc, a2, out);
  similarity_kernel<<<(513 * 513 + 255) / 256, 256, 0, stream>>>(desc, a2, K, Kt);
  for (int it = 0; it < 20; ++it) {
    matvec_div_kernel<<<513, 64, 0, stream>>>(K, bb, aa);   // a = mu / (K b)
    matvec_div_kernel<<<513, 64, 0, stream>>>(Kt, aa, bb);  // b = nu / (K^T a)
  }
  probs_kernel<<<(513 * 513 + 255) / 256, 256, 0, stream>>>(K, aa, bb, out + 2048);
}

// Round 9
// 318.374 us; speedup vs baseline: 2.1851x; 1.2345x over previous
//
#include <hip/hip_runtime.h>
#include <math.h>

#define IMH 480
#define IMW 640
#define HW (IMH*IMW)
#define KPT 512
#define DESC 256
#define CAP 12288
#define NMSR 3

// ---------------------------------------------------------------- MT19937
// Replicates np.random.RandomState(42).uniform(-8,8,(256,4)) -> round -> int.
__global__ void init_offsets_kernel(int* __restrict__ offs) {
  __shared__ unsigned int mt[624];
  __shared__ unsigned int old[624];
  __shared__ unsigned int tp[2496];   // 4 generations x 624 tempered draws
  const int tid = threadIdx.x;
  if (tid == 0) {
    unsigned int s = 42u;
    for (int i = 0; i < 624; ++i) { mt[i] = s; s = 1812433253u * (s ^ (s >> 30)) + (unsigned)i + 1u; }
  }
  __syncthreads();
  for (int g = 0; g < 4; ++g) {
    for (int k = tid; k < 624; k += 256) old[k] = mt[k];
    __syncthreads();
    for (int k = tid; k < 227; k += 256) {
      unsigned int y = (old[k] & 0x80000000u) | (old[k + 1] & 0x7fffffffu);
      mt[k] = old[k + 397] ^ (y >> 1) ^ ((y & 1u) ? 0x9908b0dfu : 0u);
    }
    __syncthreads();
    for (int k = 227 + tid; k < 454; k += 256) {
      unsigned int y = (old[k] & 0x80000000u) | (old[k + 1] & 0x7fffffffu);
      mt[k] = mt[k - 227] ^ (y >> 1) ^ ((y & 1u) ? 0x9908b0dfu : 0u);
    }
    __syncthreads();
    for (int k = 454 + tid; k < 623; k += 256) {
      unsigned int y = (old[k] & 0x80000000u) | (old[k + 1] & 0x7fffffffu);
      mt[k] = mt[k - 227] ^ (y >> 1) ^ ((y & 1u) ? 0x9908b0dfu : 0u);
    }
    __syncthreads();
    if (tid == 0) {
      unsigned int y = (old[623] & 0x80000000u) | (mt[0] & 0x7fffffffu);
      mt[623] = mt[396] ^ (y >> 1) ^ ((y & 1u) ? 0x9908b0dfu : 0u);
    }
    __syncthreads();
    for (int k = tid; k < 624; k += 256) {
      unsigned int y = mt[k];
      y ^= (y >> 11);
      y ^= (y << 7)  & 0x9d2c5680u;
      y ^= (y << 15) & 0xefc60000u;
      y ^= (y >> 18);
      tp[g * 624 + k] = y;
    }
    __syncthreads();
  }
  for (int i = tid; i < 1024; i += 256) {
    unsigned int a = tp[2 * i] >> 5, b = tp[2 * i + 1] >> 6;
    double r = ((double)a * 67108864.0 + (double)b) / 9007199254740992.0;
    offs[i] = (int)rint(-8.0 + 16.0 * r);
  }
}

__global__ void init_misc_kernel(int* __restrict__ counts, float* __restrict__ sel_val,
                                 int* __restrict__ sel_idx, float* __restrict__ a,
                                 float* __restrict__ b, int* __restrict__ rank_arr) {
  int t = blockIdx.x * blockDim.x + threadIdx.x;
  if (t < 2) counts[t] = 0;
  if (t < 2 * KPT) { sel_val[t] = 0.f; sel_idx[t] = -1; }
  if (t < 513) { a[t] = 1.f; b[t] = 1.f; }   // b=exp(v)=1 initial; a overwritten first phase
  for (int i = t; i < 2 * CAP; i += 16384) rank_arr[i] = 0;
}

// ---------------------------------------------------------------- fused detector + NMS
// 64x8 output tiles, image staged once with halo 5 (3 nms + 2 sobel/box).
// Scores computed in LDS with BIT-IDENTICAL arithmetic to the reference
// detector (same a[5][5] layout, same op order) so selection is unchanged.
// Candidates aggregated per-block in LDS -> ONE global atomicAdd per block.
#define FTW 64
#define FTH 8
__global__ void det_nms_kernel(const float* __restrict__ img0, const float* __restrict__ img1,
                               float* __restrict__ smooth,
                               float* __restrict__ cand_val, int* __restrict__ cand_idx,
                               int* __restrict__ counts) {
  const int b = blockIdx.z;
  const int x0 = blockIdx.x * FTW;
  const int y0 = blockIdx.y * FTH;
  const float* __restrict__ img = b ? img1 : img0;
  __shared__ float im[(FTH + 10) * (FTW + 10)];   // 18 x 74 image stage (0 OOB)
  __shared__ float scs[(FTH + 6) * (FTW + 6)];    // 14 x 70 scores (-inf OOB)
  __shared__ float hm[(FTH + 6) * FTW];           // 14 x 64 horizontal 7-max
  __shared__ float lval[128];
  __shared__ int lidx[128];
  __shared__ int lcnt, gbase;
  const int tid = threadIdx.x;
  if (tid == 0) lcnt = 0;
  for (int i = tid; i < 18 * 74; i += 256) {
    int ly = i / 74, lx = i - ly * 74;
    int gy = y0 + ly - 5, gx = x0 + lx - 5;
    im[i] = (gy >= 0 && gy < IMH && gx >= 0 && gx < IMW) ? img[gy * IMW + gx] : 0.f;
  }
  __syncthreads();
  for (int i = tid; i < 14 * 70; i += 256) {
    int ly = i / 70, lx = i - ly * 70;
    int gy = y0 + ly - 3, gx = x0 + lx - 3;
    float sc;
    if (gy < 0 || gy >= IMH || gx < 0 || gx >= IMW) {
      sc = -INFINITY;                 // reference NMS pads with -inf
    } else {
      float a[5][5];
      #pragma unroll
      for (int ii = 0; ii < 5; ++ii)
        #pragma unroll
        for (int jj = 0; jj < 5; ++jj)
          a[ii][jj] = im[(ly + ii) * 74 + lx + jj];
      float sm = 0.f;
      #pragma unroll
      for (int ii = 0; ii < 5; ++ii)
        #pragma unroll
        for (int jj = 0; jj < 5; ++jj) sm += a[ii][jj];
      if (ly >= 3 && ly < 3 + FTH && lx >= 3 && lx < 3 + FTW)
        smooth[b * HW + gy * IMW + gx] = sm * (1.f / 25.f);
      float sxx = 0.f, syy = 0.f, sxy = 0.f;
      #pragma unroll
      for (int cy = -1; cy <= 1; ++cy) {
        #pragma unroll
        for (int cx = -1; cx <= 1; ++cx) {
          int yy = gy + cy, xx = gx + cx;
          if (yy < 0 || yy >= IMH || xx < 0 || xx >= IMW) continue;  // zero-pad box conv
          int iu = cy + 2, iv = cx + 2;
          float ix = (a[iu - 1][iv + 1] - a[iu - 1][iv - 1])
                   + 2.f * (a[iu][iv + 1] - a[iu][iv - 1])
                   + (a[iu + 1][iv + 1] - a[iu + 1][iv - 1]);
          float iy = (a[iu + 1][iv - 1] + 2.f * a[iu + 1][iv] + a[iu + 1][iv + 1])
                   - (a[iu - 1][iv - 1] + 2.f * a[iu - 1][iv] + a[iu - 1][iv + 1]);
          sxx += ix * ix; syy += iy * iy; sxy += ix * iy;
        }
      }
      sxx *= (1.f / 9.f); syy *= (1.f / 9.f); sxy *= (1.f / 9.f);
      float half_tr = 0.5f * (sxx + syy);
      float hd = 0.5f * (sxx - syy);
      sc = half_tr - sqrtf(hd * hd + sxy * sxy + 1e-12f);
    }
    scs[i] = sc;
  }
  __syncthreads();
  for (int i = tid; i < 14 * 64; i += 256) {
    int ly = i / 64, lx = i - ly * 64;
    const float* r = scs + ly * 70 + lx;
    float m = r[0];
    #pragma unroll
    for (int d = 1; d < 7; ++d) m = fmaxf(m, r[d]);
    hm[i] = m;
  }
  __syncthreads();
  for (int i = tid; i < FTH * FTW; i += 256) {
    int ly = i >> 6, lx = i & 63;
    float s = scs[(ly + 3) * 70 + lx + 3];
    if (s > 0.f) {
      float m = hm[ly * 64 + lx];
      #pragma unroll
      for (int d = 1; d < 7; ++d) m = fmaxf(m, hm[(ly + d) * 64 + lx]);
      if (s >= m - 1e-7f) {
        int slot = atomicAdd(&lcnt, 1);
        if (slot < 128) { lval[slot] = s; lidx[slot] = (y0 + ly) * IMW + (x0 + lx); }
      }
    }
  }
  __syncthreads();
  if (tid == 0) gbase = atomicAdd(&counts[b], min(lcnt, 128));
  __syncthreads();
  int nc = min(lcnt, 128);
  for (int i = tid; i < nc; i += 256) {
    int slot = gbase + i;
    if (slot < CAP) {
      cand_val[b * CAP + slot] = lval[i];
      cand_idx[b * CAP + slot] = lidx[i];
    }
  }
}

// ---------------------------------------------------------------- top-512: 2D-tiled rank count
__global__ void rank_partial_kernel(const float* __restrict__ cand_val,
                                    const int* __restrict__ cand_idx,
                                    const int* __restrict__ counts,
                                    int* __restrict__ rank_arr) {
  int b = blockIdx.z;
  int n = counts[b]; if (n > CAP) n = CAP;
  if ((int)(blockIdx.x * 256) >= n || (int)(blockIdx.y * 256) >= n) return;
  const float* cv = cand_val + b * CAP;
  const int* ci = cand_idx + b * CAP;
  int i = blockIdx.x * 256 + threadIdx.x;
  int j = blockIdx.y * 256 + threadIdx.x;
  __shared__ unsigned long long sk[256];
  sk[threadIdx.x] = (j < n)
      ? (((unsigned long long)__float_as_uint(cv[j]) << 32) | (0xFFFFFFFFu - (unsigned)ci[j]))
      : 0ull;
  __syncthreads();
  if (i >= n) return;
  unsigned long long ki = ((unsigned long long)__float_as_uint(cv[i]) << 32)
                        | (0xFFFFFFFFu - (unsigned)ci[i]);
  int r = 0;
  #pragma unroll 8
  for (int t = 0; t < 256; ++t) r += (sk[t] > ki) ? 1 : 0;
  atomicAdd(&rank_arr[b * CAP + i], r);
}

__global__ void scatter_topk_kernel(const float* __restrict__ cand_val,
                                    const int* __restrict__ cand_idx,
                                    const int* __restrict__ counts,
                                    const int* __restrict__ rank_arr,
                                    float* __restrict__ sel_val, int* __restrict__ sel_idx) {
  int b = blockIdx.y;
  int n = counts[b]; if (n > CAP) n = CAP;
  int i = blockIdx.x * 256 + threadIdx.x;
  if (i >= n) return;
  int r = rank_arr[b * CAP + i];
  if (r < KPT) {
    sel_val[b * KPT + r] = cand_val[b * CAP + i];
    sel_idx[b * KPT + r] = cand_idx[b * CAP + i];
  }
}

// ---------------------------------------------------------------- kp out + BAD desc + L2 norm
__global__ void kp_desc_kernel(const float* __restrict__ sel_val, const int* __restrict__ sel_idx,
                               const float* __restrict__ smooth, const int* __restrict__ offs,
                               float* __restrict__ desc, float* __restrict__ a2_out,
                               float* __restrict__ out) {
  int blk = blockIdx.x;
  int b = blk >> 9;
  int k = blk & 511;
  int lane = threadIdx.x;
  float val = sel_val[b * KPT + k];
  int idx = sel_idx[b * KPT + k];
  bool valid = (val > 0.f) && (idx >= 0);
  int y = 0, x = 0;
  if (valid) { y = idx / IMW; x = idx - y * IMW; }
  const float* sm = smooth + b * HW;
  float d[4];
  #pragma unroll
  for (int t2 = 0; t2 < 4; ++t2) {
    int pp = (lane << 2) + t2;
    int oy1 = offs[4 * pp + 0], ox1 = offs[4 * pp + 1];
    int oy2 = offs[4 * pp + 2], ox2 = offs[4 * pp + 3];
    int ya = min(max(y + oy1, 0), IMH - 1), xa = min(max(x + ox1, 0), IMW - 1);
    int yb = min(max(y + oy2, 0), IMH - 1), xb = min(max(x + ox2, 0), IMW - 1);
    float v2 = sm[ya * IMW + xa] - sm[yb * IMW + xb];
    d[t2] = valid ? v2 : 0.f;
  }
  float ss = d[0] * d[0] + d[1] * d[1] + d[2] * d[2] + d[3] * d[3];
  #pragma unroll
  for (int off = 32; off; off >>= 1) ss += __shfl_down(ss, off);
  ss = __shfl(ss, 0);
  float scale = 1.f / (sqrtf(ss) + 1e-8f);
  float* dd = desc + (size_t)(b * KPT + k) * DESC;
  #pragma unroll
  for (int t2 = 0; t2 < 4; ++t2) dd[(lane << 2) + t2] = d[t2] * scale;
  if (lane == 0) {
    a2_out[b * KPT + k] = ss * scale * scale;
    float* kp = out + b * (2 * KPT) + k * 2;
    kp[0] = valid ? (float)y : -1.f;
    kp[1] = valid ? (float)x : -1.f;
  }
}

// ---------------------------------------------------------------- K = exp(sim), plus K^T for coalesced column phase
__global__ void similarity_kernel(const float* __restrict__ desc, const float* __restrict__ a2,
                                  float* __restrict__ K, float* __restrict__ Kt) {
  int t = blockIdx.x * blockDim.x + threadIdx.x;
  if (t >= 513 * 513) return;
  int k = t / 513;
  int l = t - k * 513;
  float z;
  if (k == KPT || l == KPT) {
    z = 1.0f;
  } else {
    const float* d1 = desc + (size_t)k * DESC;
    const float* d2 = desc + (size_t)(KPT + l) * DESC;
    float dot = 0.f;
    #pragma unroll 8
    for (int d = 0; d < DESC; ++d) dot += d1[d] * d2[d];
    float sq = a2[k] + a2[KPT + l] - 2.f * dot;
    sq = fmaxf(sq, 0.f);
    z = -sqrtf(sq + 1e-12f);
  }
  float e = expf(z);        // Z in [-2,1] -> K in [0.135, 2.72], fp32-safe
  K[t] = e;
  Kt[(size_t)l * 513 + k] = e;
}

// ---------------------------------------------------------------- sinkhorn, linear domain, multi-dispatch
// a = mu / (K b);  b = nu / (K^T a);  probs = K * a * b * 1024.
// Dispatch boundary IS the grid barrier (~2 us, graph-amortized) — every
// hand-rolled cross-XCD barrier measured 8-12 us/sync (R4/R5/R6).
__global__ void matvec_div_kernel(const float* __restrict__ M, const float* __restrict__ x,
                                  float* __restrict__ y) {
  const int r = blockIdx.x;          // 0..512
  const int lane = threadIdx.x;      // one wave
  const float* row = M + (size_t)r * 513;
  float s = 0.f;
  for (int i = lane; i < 513; i += 64) s += row[i] * x[i];
  #pragma unroll
  for (int off = 32; off; off >>= 1) s += __shfl_xor(s, off);
  if (lane == 0) {
    const float mu = (r == KPT) ? 0.5f : (1.0f / 1024.0f);
    y[r] = mu / s;
  }
}

__global__ void probs_kernel(const float* __restrict__ K, const float* __restrict__ a,
                             const float* __restrict__ b, float* __restrict__ out) {
  int t = blockIdx.x * blockDim.x + threadIdx.x;
  if (t >= 513 * 513) return;
  int k = t / 513;
  int l = t - k * 513;
  out[t] = K[t] * (a[k] * 1024.f) * b[l];
}

// ---------------------------------------------------------------- launch
extern "C" void kernel_launch(void* const* d_in, const int* in_sizes, int n_in,
                              void* d_out, int out_size, void* d_ws, size_t ws_size,
                              hipStream_t stream) {
  const float* img1 = (const float*)d_in[0];
  const float* img2 = (const float*)d_in[1];
  float* out = (float*)d_out;

  char* p = (char*)d_ws;
  auto alloc = [&](size_t bytes) { char* r = p; p += (bytes + 255) & ~(size_t)255; return r; };
  int*   offs     = (int*)alloc(1024 * 4);
  int*   counts   = (int*)alloc(2 * 4);
  float* sel_val  = (float*)alloc(2 * KPT * 4);
  int*   sel_idx  = (int*)alloc(2 * KPT * 4);
  float* aa       = (float*)alloc(513 * 4);
  float* bb       = (float*)alloc(513 * 4);
  float* a2       = (float*)alloc(2 * KPT * 4);
  float* smooth   = (float*)alloc((size_t)2 * HW * 4);
  float* cand_val = (float*)alloc((size_t)2 * CAP * 4);
  int*   cand_idx = (int*)alloc((size_t)2 * CAP * 4);
  int*   rank_arr = (int*)alloc((size_t)2 * CAP * 4);
  float* desc     = (float*)alloc((size_t)2 * KPT * DESC * 4);
  float* K        = (float*)alloc((size_t)513 * 513 * 4);
  float* Kt       = (float*)alloc((size_t)513 * 513 * 4);

  init_offsets_kernel<<<1, 256, 0, stream>>>(offs);
  init_misc_kernel<<<64, 256, 0, stream>>>(counts, sel_val, sel_idx, aa, bb, rank_arr);
  det_nms_kernel<<<dim3(IMW / FTW, IMH / FTH, 2), 256, 0, stream>>>(img1, img2, smooth,
                                                                    cand_val, cand_idx, counts);
  rank_partial_kernel<<<dim3(CAP / 256, CAP / 256, 2), 256, 0, stream>>>(cand_val, cand_idx, counts, rank_arr);
  scatter_topk_kernel<<<dim3(CAP / 256, 2), 256, 0, stream>>>(cand_val, cand_idx, counts, rank_arr, sel_val, sel_idx);
  kp_desc_kernel<<<1024, 64, 0, stream>>>(sel_val, sel_idx, smooth, offs, desc, a2, out);
  similarity_kernel<<<(513 * 513 + 255) / 256, 256, 0, stream>>>(desc, a2, K, Kt);
  for (int it = 0; it < 20; ++it) {
    matvec_div_kernel<<<513, 64, 0, stream>>>(K, bb, aa);   // a = mu / (K b)
    matvec_div_kernel<<<513, 64, 0, stream>>>(Kt, aa, bb);  // b = nu / (K^T a)
  }
  probs_kernel<<<(513 * 513 + 255) / 256, 256, 0, stream>>>(K, aa, bb, out + 2048);
}

// Round 10
// 316.985 us; speedup vs baseline: 2.1947x; 1.0044x over previous
//
#include <hip/hip_runtime.h>
#include <math.h>

#define IMH 480
#define IMW 640
#define HW (IMH*IMW)
#define KPT 512
#define DESC 256
#define CAP 12288
#define NMSR 3

// ---------------------------------------------------------------- MT19937
// Replicates np.random.RandomState(42).uniform(-8,8,(256,4)) -> round -> int.
__global__ void init_offsets_kernel(int* __restrict__ offs) {
  __shared__ unsigned int mt[624];
  __shared__ unsigned int old[624];
  __shared__ unsigned int tp[2496];   // 4 generations x 624 tempered draws
  const int tid = threadIdx.x;
  if (tid == 0) {
    unsigned int s = 42u;
    for (int i = 0; i < 624; ++i) { mt[i] = s; s = 1812433253u * (s ^ (s >> 30)) + (unsigned)i + 1u; }
  }
  __syncthreads();
  for (int g = 0; g < 4; ++g) {
    for (int k = tid; k < 624; k += 256) old[k] = mt[k];
    __syncthreads();
    for (int k = tid; k < 227; k += 256) {
      unsigned int y = (old[k] & 0x80000000u) | (old[k + 1] & 0x7fffffffu);
      mt[k] = old[k + 397] ^ (y >> 1) ^ ((y & 1u) ? 0x9908b0dfu : 0u);
    }
    __syncthreads();
    for (int k = 227 + tid; k < 454; k += 256) {
      unsigned int y = (old[k] & 0x80000000u) | (old[k + 1] & 0x7fffffffu);
      mt[k] = mt[k - 227] ^ (y >> 1) ^ ((y & 1u) ? 0x9908b0dfu : 0u);
    }
    __syncthreads();
    for (int k = 454 + tid; k < 623; k += 256) {
      unsigned int y = (old[k] & 0x80000000u) | (old[k + 1] & 0x7fffffffu);
      mt[k] = mt[k - 227] ^ (y >> 1) ^ ((y & 1u) ? 0x9908b0dfu : 0u);
    }
    __syncthreads();
    if (tid == 0) {
      unsigned int y = (old[623] & 0x80000000u) | (mt[0] & 0x7fffffffu);
      mt[623] = mt[396] ^ (y >> 1) ^ ((y & 1u) ? 0x9908b0dfu : 0u);
    }
    __syncthreads();
    for (int k = tid; k < 624; k += 256) {
      unsigned int y = mt[k];
      y ^= (y >> 11);
      y ^= (y << 7)  & 0x9d2c5680u;
      y ^= (y << 15) & 0xefc60000u;
      y ^= (y >> 18);
      tp[g * 624 + k] = y;
    }
    __syncthreads();
  }
  for (int i = tid; i < 1024; i += 256) {
    unsigned int a = tp[2 * i] >> 5, b = tp[2 * i + 1] >> 6;
    double r = ((double)a * 67108864.0 + (double)b) / 9007199254740992.0;
    offs[i] = (int)rint(-8.0 + 16.0 * r);
  }
}

__global__ void init_misc_kernel(int* __restrict__ counts, float* __restrict__ sel_val,
                                 int* __restrict__ sel_idx, float* __restrict__ a,
                                 float* __restrict__ b, int* __restrict__ rank_arr,
                                 float* __restrict__ K, float* __restrict__ Kt) {
  int t = blockIdx.x * blockDim.x + threadIdx.x;
  if (t < 2) counts[t] = 0;
  if (t < 2 * KPT) { sel_val[t] = 0.f; sel_idx[t] = -1; }
  if (t < 513) { a[t] = 1.f; b[t] = 1.f; }   // b=exp(v)=1 initial; a overwritten first phase
  if (t < 513) {
    // dustbin row/col of the linear-domain kernel matrix: exp(UNUSED/EPS)=exp(1)
    float e = expf(1.0f);
    K[(size_t)KPT * 513 + t] = e;  K[(size_t)t * 513 + KPT] = e;
    Kt[(size_t)KPT * 513 + t] = e; Kt[(size_t)t * 513 + KPT] = e;
  }
  for (int i = t; i < 2 * CAP; i += 16384) rank_arr[i] = 0;
}

// ---------------------------------------------------------------- fused detector + NMS
#define FTW 64
#define FTH 8
__global__ void det_nms_kernel(const float* __restrict__ img0, const float* __restrict__ img1,
                               float* __restrict__ smooth,
                               float* __restrict__ cand_val, int* __restrict__ cand_idx,
                               int* __restrict__ counts) {
  const int b = blockIdx.z;
  const int x0 = blockIdx.x * FTW;
  const int y0 = blockIdx.y * FTH;
  const float* __restrict__ img = b ? img1 : img0;
  __shared__ float im[(FTH + 10) * (FTW + 10)];   // 18 x 74 image stage (0 OOB)
  __shared__ float scs[(FTH + 6) * (FTW + 6)];    // 14 x 70 scores (-inf OOB)
  __shared__ float hm[(FTH + 6) * FTW];           // 14 x 64 horizontal 7-max
  __shared__ float lval[128];
  __shared__ int lidx[128];
  __shared__ int lcnt, gbase;
  const int tid = threadIdx.x;
  if (tid == 0) lcnt = 0;
  for (int i = tid; i < 18 * 74; i += 256) {
    int ly = i / 74, lx = i - ly * 74;
    int gy = y0 + ly - 5, gx = x0 + lx - 5;
    im[i] = (gy >= 0 && gy < IMH && gx >= 0 && gx < IMW) ? img[gy * IMW + gx] : 0.f;
  }
  __syncthreads();
  for (int i = tid; i < 14 * 70; i += 256) {
    int ly = i / 70, lx = i - ly * 70;
    int gy = y0 + ly - 3, gx = x0 + lx - 3;
    float sc;
    if (gy < 0 || gy >= IMH || gx < 0 || gx >= IMW) {
      sc = -INFINITY;                 // reference NMS pads with -inf
    } else {
      float a[5][5];
      #pragma unroll
      for (int ii = 0; ii < 5; ++ii)
        #pragma unroll
        for (int jj = 0; jj < 5; ++jj)
          a[ii][jj] = im[(ly + ii) * 74 + lx + jj];
      float sm = 0.f;
      #pragma unroll
      for (int ii = 0; ii < 5; ++ii)
        #pragma unroll
        for (int jj = 0; jj < 5; ++jj) sm += a[ii][jj];
      if (ly >= 3 && ly < 3 + FTH && lx >= 3 && lx < 3 + FTW)
        smooth[b * HW + gy * IMW + gx] = sm * (1.f / 25.f);
      float sxx = 0.f, syy = 0.f, sxy = 0.f;
      #pragma unroll
      for (int cy = -1; cy <= 1; ++cy) {
        #pragma unroll
        for (int cx = -1; cx <= 1; ++cx) {
          int yy = gy + cy, xx = gx + cx;
          if (yy < 0 || yy >= IMH || xx < 0 || xx >= IMW) continue;  // zero-pad box conv
          int iu = cy + 2, iv = cx + 2;
          float ix = (a[iu - 1][iv + 1] - a[iu - 1][iv - 1])
                   + 2.f * (a[iu][iv + 1] - a[iu][iv - 1])
                   + (a[iu + 1][iv + 1] - a[iu + 1][iv - 1]);
          float iy = (a[iu + 1][iv - 1] + 2.f * a[iu + 1][iv] + a[iu + 1][iv + 1])
                   - (a[iu - 1][iv - 1] + 2.f * a[iu - 1][iv] + a[iu - 1][iv + 1]);
          sxx += ix * ix; syy += iy * iy; sxy += ix * iy;
        }
      }
      sxx *= (1.f / 9.f); syy *= (1.f / 9.f); sxy *= (1.f / 9.f);
      float half_tr = 0.5f * (sxx + syy);
      float hd = 0.5f * (sxx - syy);
      sc = half_tr - sqrtf(hd * hd + sxy * sxy + 1e-12f);
    }
    scs[i] = sc;
  }
  __syncthreads();
  for (int i = tid; i < 14 * 64; i += 256) {
    int ly = i / 64, lx = i - ly * 64;
    const float* r = scs + ly * 70 + lx;
    float m = r[0];
    #pragma unroll
    for (int d = 1; d < 7; ++d) m = fmaxf(m, r[d]);
    hm[i] = m;
  }
  __syncthreads();
  for (int i = tid; i < FTH * FTW; i += 256) {
    int ly = i >> 6, lx = i & 63;
    float s = scs[(ly + 3) * 70 + lx + 3];
    if (s > 0.f) {
      float m = hm[ly * 64 + lx];
      #pragma unroll
      for (int d = 1; d < 7; ++d) m = fmaxf(m, hm[(ly + d) * 64 + lx]);
      if (s >= m - 1e-7f) {
        int slot = atomicAdd(&lcnt, 1);
        if (slot < 128) { lval[slot] = s; lidx[slot] = (y0 + ly) * IMW + (x0 + lx); }
      }
    }
  }
  __syncthreads();
  if (tid == 0) gbase = atomicAdd(&counts[b], min(lcnt, 128));
  __syncthreads();
  int nc = min(lcnt, 128);
  for (int i = tid; i < nc; i += 256) {
    int slot = gbase + i;
    if (slot < CAP) {
      cand_val[b * CAP + slot] = lval[i];
      cand_idx[b * CAP + slot] = lidx[i];
    }
  }
}

// ---------------------------------------------------------------- top-512: 2D-tiled rank count
__global__ void rank_partial_kernel(const float* __restrict__ cand_val,
                                    const int* __restrict__ cand_idx,
                                    const int* __restrict__ counts,
                                    int* __restrict__ rank_arr) {
  int b = blockIdx.z;
  int n = counts[b]; if (n > CAP) n = CAP;
  if ((int)(blockIdx.x * 256) >= n || (int)(blockIdx.y * 256) >= n) return;
  const float* cv = cand_val + b * CAP;
  const int* ci = cand_idx + b * CAP;
  int i = blockIdx.x * 256 + threadIdx.x;
  int j = blockIdx.y * 256 + threadIdx.x;
  __shared__ unsigned long long sk[256];
  sk[threadIdx.x] = (j < n)
      ? (((unsigned long long)__float_as_uint(cv[j]) << 32) | (0xFFFFFFFFu - (unsigned)ci[j]))
      : 0ull;
  __syncthreads();
  if (i >= n) return;
  unsigned long long ki = ((unsigned long long)__float_as_uint(cv[i]) << 32)
                        | (0xFFFFFFFFu - (unsigned)ci[i]);
  int r = 0;
  #pragma unroll 8
  for (int t = 0; t < 256; ++t) r += (sk[t] > ki) ? 1 : 0;
  atomicAdd(&rank_arr[b * CAP + i], r);
}

__global__ void scatter_topk_kernel(const float* __restrict__ cand_val,
                                    const int* __restrict__ cand_idx,
                                    const int* __restrict__ counts,
                                    const int* __restrict__ rank_arr,
                                    float* __restrict__ sel_val, int* __restrict__ sel_idx) {
  int b = blockIdx.y;
  int n = counts[b]; if (n > CAP) n = CAP;
  int i = blockIdx.x * 256 + threadIdx.x;
  if (i >= n) return;
  int r = rank_arr[b * CAP + i];
  if (r < KPT) {
    sel_val[b * KPT + r] = cand_val[b * CAP + i];
    sel_idx[b * KPT + r] = cand_idx[b * CAP + i];
  }
}

// ---------------------------------------------------------------- kp out + BAD desc + L2 norm
__global__ void kp_desc_kernel(const float* __restrict__ sel_val, const int* __restrict__ sel_idx,
                               const float* __restrict__ smooth, const int* __restrict__ offs,
                               float* __restrict__ desc, float* __restrict__ a2_out,
                               float* __restrict__ out) {
  int blk = blockIdx.x;
  int b = blk >> 9;
  int k = blk & 511;
  int lane = threadIdx.x;
  float val = sel_val[b * KPT + k];
  int idx = sel_idx[b * KPT + k];
  bool valid = (val > 0.f) && (idx >= 0);
  int y = 0, x = 0;
  if (valid) { y = idx / IMW; x = idx - y * IMW; }
  const float* sm = smooth + b * HW;
  float d[4];
  #pragma unroll
  for (int t2 = 0; t2 < 4; ++t2) {
    int pp = (lane << 2) + t2;
    int oy1 = offs[4 * pp + 0], ox1 = offs[4 * pp + 1];
    int oy2 = offs[4 * pp + 2], ox2 = offs[4 * pp + 3];
    int ya = min(max(y + oy1, 0), IMH - 1), xa = min(max(x + ox1, 0), IMW - 1);
    int yb = min(max(y + oy2, 0), IMH - 1), xb = min(max(x + ox2, 0), IMW - 1);
    float v2 = sm[ya * IMW + xa] - sm[yb * IMW + xb];
    d[t2] = valid ? v2 : 0.f;
  }
  float ss = d[0] * d[0] + d[1] * d[1] + d[2] * d[2] + d[3] * d[3];
  #pragma unroll
  for (int off = 32; off; off >>= 1) ss += __shfl_down(ss, off);
  ss = __shfl(ss, 0);
  float scale = 1.f / (sqrtf(ss) + 1e-8f);
  float* dd = desc + (size_t)(b * KPT + k) * DESC;
  #pragma unroll
  for (int t2 = 0; t2 < 4; ++t2) dd[(lane << 2) + t2] = d[t2] * scale;
  if (lane == 0) {
    a2_out[b * KPT + k] = ss * scale * scale;
    float* kp = out + b * (2 * KPT) + k * 2;
    kp[0] = valid ? (float)y : -1.f;
    kp[1] = valid ? (float)x : -1.f;
  }
}

// ---------------------------------------------------------------- similarity: LDS-tiled GEMM
// K[k][l] = exp(-sqrt(max(a2[k]+a2[512+l]-2*dot,0)+1e-12)); interior only
// (dustbin row/col filled by init_misc — constant exp(1)).
// 64x64 output tile/block, 4x4 regs/thread, K-chunks of 32 staged transposed.
#define SPAD 68   // LDS row pitch: 16B-aligned float4 reads, <=4-way stage conflict
__global__ __launch_bounds__(256) void similarity_tiled_kernel(
    const float* __restrict__ desc, const float* __restrict__ a2,
    float* __restrict__ K, float* __restrict__ Kt) {
  __shared__ float As[32 * SPAD];
  __shared__ float Bs[32 * SPAD];
  const int tx = threadIdx.x & 15;
  const int ty = threadIdx.x >> 4;
  const int row0 = blockIdx.y * 64;   // k-tile origin
  const int col0 = blockIdx.x * 64;   // l-tile origin
  float acc[4][4] = {};
  for (int kc = 0; kc < DESC; kc += 32) {
    for (int i = threadIdx.x; i < 64 * 32; i += 256) {
      int r = i >> 5, c = i & 31;
      As[c * SPAD + r] = desc[(size_t)(row0 + r) * DESC + kc + c];
      Bs[c * SPAD + r] = desc[(size_t)(KPT + col0 + r) * DESC + kc + c];
    }
    __syncthreads();
    #pragma unroll 8
    for (int kk = 0; kk < 32; ++kk) {
      const float4 av = *(const float4*)&As[kk * SPAD + ty * 4];
      const float4 bv = *(const float4*)&Bs[kk * SPAD + tx * 4];
      acc[0][0] += av.x * bv.x; acc[0][1] += av.x * bv.y; acc[0][2] += av.x * bv.z; acc[0][3] += av.x * bv.w;
      acc[1][0] += av.y * bv.x; acc[1][1] += av.y * bv.y; acc[1][2] += av.y * bv.z; acc[1][3] += av.y * bv.w;
      acc[2][0] += av.z * bv.x; acc[2][1] += av.z * bv.y; acc[2][2] += av.z * bv.z; acc[2][3] += av.z * bv.w;
      acc[3][0] += av.w * bv.x; acc[3][1] += av.w * bv.y; acc[3][2] += av.w * bv.z; acc[3][3] += av.w * bv.w;
    }
    __syncthreads();
  }
  float a2k[4], b2l[4];
  #pragma unroll
  for (int i = 0; i < 4; ++i) {
    a2k[i] = a2[row0 + ty * 4 + i];
    b2l[i] = a2[KPT + col0 + tx * 4 + i];
  }
  #pragma unroll
  for (int i = 0; i < 4; ++i) {
    int gk = row0 + ty * 4 + i;
    #pragma unroll
    for (int j = 0; j < 4; ++j) {
      int gl = col0 + tx * 4 + j;
      float sq = fmaxf(a2k[i] + b2l[j] - 2.f * acc[i][j], 0.f);
      float e = expf(-sqrtf(sq + 1e-12f));   // Z in [-2,0] -> K in [0.135,1]
      K[(size_t)gk * 513 + gl] = e;
      Kt[(size_t)gl * 513 + gk] = e;
    }
  }
}

// ---------------------------------------------------------------- sinkhorn, linear domain, multi-dispatch
// a = mu / (K b);  b = nu / (K^T a);  probs = K * a * b * 1024.
// Dispatch boundary IS the grid barrier (~2 us, graph-amortized) — every
// hand-rolled cross-XCD barrier measured 8-12 us/sync (R4/R5/R6).
__global__ void matvec_div_kernel(const float* __restrict__ M, const float* __restrict__ x,
                                  float* __restrict__ y) {
  const int r = blockIdx.x;          // 0..512
  const int lane = threadIdx.x;      // one wave
  const float* row = M + (size_t)r * 513;
  float s = 0.f;
  for (int i = lane; i < 513; i += 64) s += row[i] * x[i];
  #pragma unroll
  for (int off = 32; off; off >>= 1) s += __shfl_xor(s, off);
  if (lane == 0) {
    const float mu = (r == KPT) ? 0.5f : (1.0f / 1024.0f);
    y[r] = mu / s;
  }
}

__global__ void probs_kernel(const float* __restrict__ K, const float* __restrict__ a,
                             const float* __restrict__ b, float* __restrict__ out) {
  int t = blockIdx.x * blockDim.x + threadIdx.x;
  if (t >= 513 * 513) return;
  int k = t / 513;
  int l = t - k * 513;
  out[t] = K[t] * (a[k] * 1024.f) * b[l];
}

// ---------------------------------------------------------------- launch
extern "C" void kernel_launch(void* const* d_in, const int* in_sizes, int n_in,
                              void* d_out, int out_size, void* d_ws, size_t ws_size,
                              hipStream_t stream) {
  const float* img1 = (const float*)d_in[0];
  const float* img2 = (const float*)d_in[1];
  float* out = (float*)d_out;

  char* p = (char*)d_ws;
  auto alloc = [&](size_t bytes) { char* r = p; p += (bytes + 255) & ~(size_t)255; return r; };
  int*   offs     = (int*)alloc(1024 * 4);
  int*   counts   = (int*)alloc(2 * 4);
  float* sel_val  = (float*)alloc(2 * KPT * 4);
  int*   sel_idx  = (int*)alloc(2 * KPT * 4);
  float* aa       = (float*)alloc(513 * 4);
  float* bb       = (float*)alloc(513 * 4);
  float* a2       = (float*)alloc(2 * KPT * 4);
  float* smooth   = (float*)alloc((size_t)2 * HW * 4);
  float* cand_val = (float*)alloc((size_t)2 * CAP * 4);
  int*   cand_idx = (int*)alloc((size_t)2 * CAP * 4);
  int*   rank_arr = (int*)alloc((size_t)2 * CAP * 4);
  float* desc     = (float*)alloc((size_t)2 * KPT * DESC * 4);
  float* K        = (float*)alloc((size_t)513 * 513 * 4);
  float* Kt       = (float*)alloc((size_t)513 * 513 * 4);

  init_offsets_kernel<<<1, 256, 0, stream>>>(offs);
  init_misc_kernel<<<64, 256, 0, stream>>>(counts, sel_val, sel_idx, aa, bb, rank_arr, K, Kt);
  det_nms_kernel<<<dim3(IMW / FTW, IMH / FTH, 2), 256, 0, stream>>>(img1, img2, smooth,
                                                                    cand_val, cand_idx, counts);
  rank_partial_kernel<<<dim3(CAP / 256, CAP / 256, 2), 256, 0, stream>>>(cand_val, cand_idx, counts, rank_arr);
  scatter_topk_kernel<<<dim3(CAP / 256, 2), 256, 0, stream>>>(cand_val, cand_idx, counts, rank_arr, sel_val, sel_idx);
  kp_desc_kernel<<<1024, 64, 0, stream>>>(sel_val, sel_idx, smooth, offs, desc, a2, out);
  similarity_tiled_kernel<<<dim3(8, 8), 256, 0, stream>>>(desc, a2, K, Kt);
  for (int it = 0; it < 20; ++it) {
    matvec_div_kernel<<<513, 64, 0, stream>>>(K, bb, aa);   // a = mu / (K b)
    matvec_div_kernel<<<513, 64, 0, stream>>>(Kt, aa, bb);  // b = nu / (K^T a)
  }
  probs_kernel<<<(513 * 513 + 255) / 256, 256, 0, stream>>>(K, aa, bb, out + 2048);
}

// Round 11
// 291.466 us; speedup vs baseline: 2.3868x; 1.0876x over previous
//
#include <hip/hip_runtime.h>
#include <math.h>

#define IMH 480
#define IMW 640
#define HW (IMH*IMW)
#define KPT 512
#define DESC 256
#define CAP 12288
#define NMSR 3

// ---------------------------------------------------------------- MT19937
// Replicates np.random.RandomState(42).uniform(-8,8,(256,4)) -> round -> int.
__global__ void init_offsets_kernel(int* __restrict__ offs) {
  __shared__ unsigned int mt[624];
  __shared__ unsigned int old[624];
  __shared__ unsigned int tp[2496];   // 4 generations x 624 tempered draws
  const int tid = threadIdx.x;
  if (tid == 0) {
    unsigned int s = 42u;
    for (int i = 0; i < 624; ++i) { mt[i] = s; s = 1812433253u * (s ^ (s >> 30)) + (unsigned)i + 1u; }
  }
  __syncthreads();
  for (int g = 0; g < 4; ++g) {
    for (int k = tid; k < 624; k += 256) old[k] = mt[k];
    __syncthreads();
    for (int k = tid; k < 227; k += 256) {
      unsigned int y = (old[k] & 0x80000000u) | (old[k + 1] & 0x7fffffffu);
      mt[k] = old[k + 397] ^ (y >> 1) ^ ((y & 1u) ? 0x9908b0dfu : 0u);
    }
    __syncthreads();
    for (int k = 227 + tid; k < 454; k += 256) {
      unsigned int y = (old[k] & 0x80000000u) | (old[k + 1] & 0x7fffffffu);
      mt[k] = mt[k - 227] ^ (y >> 1) ^ ((y & 1u) ? 0x9908b0dfu : 0u);
    }
    __syncthreads();
    for (int k = 454 + tid; k < 623; k += 256) {
      unsigned int y = (old[k] & 0x80000000u) | (old[k + 1] & 0x7fffffffu);
      mt[k] = mt[k - 227] ^ (y >> 1) ^ ((y & 1u) ? 0x9908b0dfu : 0u);
    }
    __syncthreads();
    if (tid == 0) {
      unsigned int y = (old[623] & 0x80000000u) | (mt[0] & 0x7fffffffu);
      mt[623] = mt[396] ^ (y >> 1) ^ ((y & 1u) ? 0x9908b0dfu : 0u);
    }
    __syncthreads();
    for (int k = tid; k < 624; k += 256) {
      unsigned int y = mt[k];
      y ^= (y >> 11);
      y ^= (y << 7)  & 0x9d2c5680u;
      y ^= (y << 15) & 0xefc60000u;
      y ^= (y >> 18);
      tp[g * 624 + k] = y;
    }
    __syncthreads();
  }
  for (int i = tid; i < 1024; i += 256) {
    unsigned int a = tp[2 * i] >> 5, b = tp[2 * i + 1] >> 6;
    double r = ((double)a * 67108864.0 + (double)b) / 9007199254740992.0;
    offs[i] = (int)rint(-8.0 + 16.0 * r);
  }
}

__global__ void init_misc_kernel(int* __restrict__ counts, float* __restrict__ sel_val,
                                 int* __restrict__ sel_idx, float* __restrict__ a,
                                 float* __restrict__ b, int* __restrict__ rank_arr,
                                 float* __restrict__ K, float* __restrict__ Kt) {
  int t = blockIdx.x * blockDim.x + threadIdx.x;
  if (t < 2) counts[t] = 0;
  if (t < 2 * KPT) { sel_val[t] = 0.f; sel_idx[t] = -1; }
  if (t < 513) { a[t] = 1.f; b[t] = 1.f; }   // b=exp(v)=1 initial; a overwritten first phase
  if (t < 513) {
    // dustbin row/col of the linear-domain kernel matrix: exp(UNUSED/EPS)=exp(1)
    float e = expf(1.0f);
    K[(size_t)KPT * 513 + t] = e;  K[(size_t)t * 513 + KPT] = e;
    Kt[(size_t)KPT * 513 + t] = e; Kt[(size_t)t * 513 + KPT] = e;
  }
  for (int i = t; i < 2 * CAP; i += 16384) rank_arr[i] = 0;
}

// ---------------------------------------------------------------- fused detector + NMS
#define FTW 64
#define FTH 8
__global__ void det_nms_kernel(const float* __restrict__ img0, const float* __restrict__ img1,
                               float* __restrict__ smooth,
                               float* __restrict__ cand_val, int* __restrict__ cand_idx,
                               int* __restrict__ counts) {
  const int b = blockIdx.z;
  const int x0 = blockIdx.x * FTW;
  const int y0 = blockIdx.y * FTH;
  const float* __restrict__ img = b ? img1 : img0;
  __shared__ float im[(FTH + 10) * (FTW + 10)];   // 18 x 74 image stage (0 OOB)
  __shared__ float scs[(FTH + 6) * (FTW + 6)];    // 14 x 70 scores (-inf OOB)
  __shared__ float hm[(FTH + 6) * FTW];           // 14 x 64 horizontal 7-max
  __shared__ float lval[128];
  __shared__ int lidx[128];
  __shared__ int lcnt, gbase;
  const int tid = threadIdx.x;
  if (tid == 0) lcnt = 0;
  for (int i = tid; i < 18 * 74; i += 256) {
    int ly = i / 74, lx = i - ly * 74;
    int gy = y0 + ly - 5, gx = x0 + lx - 5;
    im[i] = (gy >= 0 && gy < IMH && gx >= 0 && gx < IMW) ? img[gy * IMW + gx] : 0.f;
  }
  __syncthreads();
  for (int i = tid; i < 14 * 70; i += 256) {
    int ly = i / 70, lx = i - ly * 70;
    int gy = y0 + ly - 3, gx = x0 + lx - 3;
    float sc;
    if (gy < 0 || gy >= IMH || gx < 0 || gx >= IMW) {
      sc = -INFINITY;                 // reference NMS pads with -inf
    } else {
      float a[5][5];
      #pragma unroll
      for (int ii = 0; ii < 5; ++ii)
        #pragma unroll
        for (int jj = 0; jj < 5; ++jj)
          a[ii][jj] = im[(ly + ii) * 74 + lx + jj];
      float sm = 0.f;
      #pragma unroll
      for (int ii = 0; ii < 5; ++ii)
        #pragma unroll
        for (int jj = 0; jj < 5; ++jj) sm += a[ii][jj];
      if (ly >= 3 && ly < 3 + FTH && lx >= 3 && lx < 3 + FTW)
        smooth[b * HW + gy * IMW + gx] = sm * (1.f / 25.f);
      float sxx = 0.f, syy = 0.f, sxy = 0.f;
      #pragma unroll
      for (int cy = -1; cy <= 1; ++cy) {
        #pragma unroll
        for (int cx = -1; cx <= 1; ++cx) {
          int yy = gy + cy, xx = gx + cx;
          if (yy < 0 || yy >= IMH || xx < 0 || xx >= IMW) continue;  // zero-pad box conv
          int iu = cy + 2, iv = cx + 2;
          float ix = (a[iu - 1][iv + 1] - a[iu - 1][iv - 1])
                   + 2.f * (a[iu][iv + 1] - a[iu][iv - 1])
                   + (a[iu + 1][iv + 1] - a[iu + 1][iv - 1]);
          float iy = (a[iu + 1][iv - 1] + 2.f * a[iu + 1][iv] + a[iu + 1][iv + 1])
                   - (a[iu - 1][iv - 1] + 2.f * a[iu - 1][iv] + a[iu - 1][iv + 1]);
          sxx += ix * ix; syy += iy * iy; sxy += ix * iy;
        }
      }
      sxx *= (1.f / 9.f); syy *= (1.f / 9.f); sxy *= (1.f / 9.f);
      float half_tr = 0.5f * (sxx + syy);
      float hd = 0.5f * (sxx - syy);
      sc = half_tr - sqrtf(hd * hd + sxy * sxy + 1e-12f);
    }
    scs[i] = sc;
  }
  __syncthreads();
  for (int i = tid; i < 14 * 64; i += 256) {
    int ly = i / 64, lx = i - ly * 64;
    const float* r = scs + ly * 70 + lx;
    float m = r[0];
    #pragma unroll
    for (int d = 1; d < 7; ++d) m = fmaxf(m, r[d]);
    hm[i] = m;
  }
  __syncthreads();
  for (int i = tid; i < FTH * FTW; i += 256) {
    int ly = i >> 6, lx = i & 63;
    float s = scs[(ly + 3) * 70 + lx + 3];
    if (s > 0.f) {
      float m = hm[ly * 64 + lx];
      #pragma unroll
      for (int d = 1; d < 7; ++d) m = fmaxf(m, hm[(ly + d) * 64 + lx]);
      if (s >= m - 1e-7f) {
        int slot = atomicAdd(&lcnt, 1);
        if (slot < 128) { lval[slot] = s; lidx[slot] = (y0 + ly) * IMW + (x0 + lx); }
      }
    }
  }
  __syncthreads();
  if (tid == 0) gbase = atomicAdd(&counts[b], min(lcnt, 128));
  __syncthreads();
  int nc = min(lcnt, 128);
  for (int i = tid; i < nc; i += 256) {
    int slot = gbase + i;
    if (slot < CAP) {
      cand_val[b * CAP + slot] = lval[i];
      cand_idx[b * CAP + slot] = lidx[i];
    }
  }
}

// ---------------------------------------------------------------- top-512: 2D-tiled rank count
__global__ void rank_partial_kernel(const float* __restrict__ cand_val,
                                    const int* __restrict__ cand_idx,
                                    const int* __restrict__ counts,
                                    int* __restrict__ rank_arr) {
  int b = blockIdx.z;
  int n = counts[b]; if (n > CAP) n = CAP;
  if ((int)(blockIdx.x * 256) >= n || (int)(blockIdx.y * 256) >= n) return;
  const float* cv = cand_val + b * CAP;
  const int* ci = cand_idx + b * CAP;
  int i = blockIdx.x * 256 + threadIdx.x;
  int j = blockIdx.y * 256 + threadIdx.x;
  __shared__ unsigned long long sk[256];
  sk[threadIdx.x] = (j < n)
      ? (((unsigned long long)__float_as_uint(cv[j]) << 32) | (0xFFFFFFFFu - (unsigned)ci[j]))
      : 0ull;
  __syncthreads();
  if (i >= n) return;
  unsigned long long ki = ((unsigned long long)__float_as_uint(cv[i]) << 32)
                        | (0xFFFFFFFFu - (unsigned)ci[i]);
  int r = 0;
  #pragma unroll 8
  for (int t = 0; t < 256; ++t) r += (sk[t] > ki) ? 1 : 0;
  atomicAdd(&rank_arr[b * CAP + i], r);
}

__global__ void scatter_topk_kernel(const float* __restrict__ cand_val,
                                    const int* __restrict__ cand_idx,
                                    const int* __restrict__ counts,
                                    const int* __restrict__ rank_arr,
                                    float* __restrict__ sel_val, int* __restrict__ sel_idx) {
  int b = blockIdx.y;
  int n = counts[b]; if (n > CAP) n = CAP;
  int i = blockIdx.x * 256 + threadIdx.x;
  if (i >= n) return;
  int r = rank_arr[b * CAP + i];
  if (r < KPT) {
    sel_val[b * KPT + r] = cand_val[b * CAP + i];
    sel_idx[b * KPT + r] = cand_idx[b * CAP + i];
  }
}

// ---------------------------------------------------------------- kp out + BAD desc + L2 norm
__global__ void kp_desc_kernel(const float* __restrict__ sel_val, const int* __restrict__ sel_idx,
                               const float* __restrict__ smooth, const int* __restrict__ offs,
                               float* __restrict__ desc, float* __restrict__ a2_out,
                               float* __restrict__ out) {
  int blk = blockIdx.x;
  int b = blk >> 9;
  int k = blk & 511;
  int lane = threadIdx.x;
  float val = sel_val[b * KPT + k];
  int idx = sel_idx[b * KPT + k];
  bool valid = (val > 0.f) && (idx >= 0);
  int y = 0, x = 0;
  if (valid) { y = idx / IMW; x = idx - y * IMW; }
  const float* sm = smooth + b * HW;
  float d[4];
  #pragma unroll
  for (int t2 = 0; t2 < 4; ++t2) {
    int pp = (lane << 2) + t2;
    int oy1 = offs[4 * pp + 0], ox1 = offs[4 * pp + 1];
    int oy2 = offs[4 * pp + 2], ox2 = offs[4 * pp + 3];
    int ya = min(max(y + oy1, 0), IMH - 1), xa = min(max(x + ox1, 0), IMW - 1);
    int yb = min(max(y + oy2, 0), IMH - 1), xb = min(max(x + ox2, 0), IMW - 1);
    float v2 = sm[ya * IMW + xa] - sm[yb * IMW + xb];
    d[t2] = valid ? v2 : 0.f;
  }
  float ss = d[0] * d[0] + d[1] * d[1] + d[2] * d[2] + d[3] * d[3];
  #pragma unroll
  for (int off = 32; off; off >>= 1) ss += __shfl_down(ss, off);
  ss = __shfl(ss, 0);
  float scale = 1.f / (sqrtf(ss) + 1e-8f);
  float* dd = desc + (size_t)(b * KPT + k) * DESC;
  #pragma unroll
  for (int t2 = 0; t2 < 4; ++t2) dd[(lane << 2) + t2] = d[t2] * scale;
  if (lane == 0) {
    a2_out[b * KPT + k] = ss * scale * scale;
    float* kp = out + b * (2 * KPT) + k * 2;
    kp[0] = valid ? (float)y : -1.f;
    kp[1] = valid ? (float)x : -1.f;
  }
}

// ---------------------------------------------------------------- similarity: LDS-tiled GEMM, 256 blocks
// 32x32 output tile/block (grid 16x16 -> every CU busy; R9's 8x8=64 blocks
// left 75% of the chip idle — that was the whole 52 us). 2x2 regs/thread,
// K-chunks of 64 staged transposed, pitch 34 (even -> aligned float2).
// Accumulation strictly k-ascending -> interior bit-identical to naive.
// Epilogue stages tile in LDS; K AND Kt written as coalesced rows.
#define CK 64
#define APITCH 34
__global__ __launch_bounds__(256) void similarity_tiled_kernel(
    const float* __restrict__ desc, const float* __restrict__ a2,
    float* __restrict__ K, float* __restrict__ Kt) {
  __shared__ float As[CK * APITCH];   // [k][row]
  __shared__ float Bs[CK * APITCH];   // [k][col]
  __shared__ float T[32 * 33];        // output tile for coalesced writes
  const int tid = threadIdx.x;
  const int tx = tid & 15;        // col-pair index
  const int ty = tid >> 4;        // row-pair index
  const int row0 = blockIdx.y * 32;
  const int col0 = blockIdx.x * 32;
  float acc[2][2] = {};
  for (int kc = 0; kc < DESC; kc += CK) {
    for (int i = tid; i < 32 * CK; i += 256) {
      int c = i & (CK - 1), r = i >> 6;   // consecutive lanes -> consecutive c: coalesced
      As[c * APITCH + r] = desc[(size_t)(row0 + r) * DESC + kc + c];
      Bs[c * APITCH + r] = desc[(size_t)(KPT + col0 + r) * DESC + kc + c];
    }
    __syncthreads();
    #pragma unroll 16
    for (int kk = 0; kk < CK; ++kk) {
      const float2 av = *(const float2*)&As[kk * APITCH + ty * 2];
      const float2 bv = *(const float2*)&Bs[kk * APITCH + tx * 2];
      acc[0][0] += av.x * bv.x; acc[0][1] += av.x * bv.y;
      acc[1][0] += av.y * bv.x; acc[1][1] += av.y * bv.y;
    }
    __syncthreads();
  }
  float a2k[2], b2l[2];
  #pragma unroll
  for (int i = 0; i < 2; ++i) {
    a2k[i] = a2[row0 + ty * 2 + i];
    b2l[i] = a2[KPT + col0 + tx * 2 + i];
  }
  #pragma unroll
  for (int i = 0; i < 2; ++i)
    #pragma unroll
    for (int j = 0; j < 2; ++j) {
      float sq = fmaxf(a2k[i] + b2l[j] - 2.f * acc[i][j], 0.f);
      T[(ty * 2 + i) * 33 + tx * 2 + j] = expf(-sqrtf(sq + 1e-12f));
    }
  __syncthreads();
  for (int i = tid; i < 1024; i += 256) {
    int r = i >> 5, c = i & 31;
    K[(size_t)(row0 + r) * 513 + col0 + c] = T[r * 33 + c];
  }
  for (int i = tid; i < 1024; i += 256) {
    int r = i & 31, c = i >> 5;
    Kt[(size_t)(col0 + c) * 513 + row0 + r] = T[r * 33 + c];
  }
}

// ---------------------------------------------------------------- sinkhorn, linear domain, multi-dispatch
// a = mu / (K b);  b = nu / (K^T a);  probs = K * a * b * 1024.
// Dispatch boundary IS the grid barrier (~2 us, graph-amortized) — every
// hand-rolled cross-XCD barrier measured 8-12 us/sync (R4/R5/R6).
__global__ void matvec_div_kernel(const float* __restrict__ M, const float* __restrict__ x,
                                  float* __restrict__ y) {
  const int r = blockIdx.x;          // 0..512
  const int lane = threadIdx.x;      // one wave
  const float* row = M + (size_t)r * 513;
  float s = 0.f;
  for (int i = lane; i < 513; i += 64) s += row[i] * x[i];
  #pragma unroll
  for (int off = 32; off; off >>= 1) s += __shfl_xor(s, off);
  if (lane == 0) {
    const float mu = (r == KPT) ? 0.5f : (1.0f / 1024.0f);
    y[r] = mu / s;
  }
}

__global__ void probs_kernel(const float* __restrict__ K, const float* __restrict__ a,
                             const float* __restrict__ b, float* __restrict__ out) {
  int t = blockIdx.x * blockDim.x + threadIdx.x;
  if (t >= 513 * 513) return;
  int k = t / 513;
  int l = t - k * 513;
  out[t] = K[t] * (a[k] * 1024.f) * b[l];
}

// ---------------------------------------------------------------- launch
extern "C" void kernel_launch(void* const* d_in, const int* in_sizes, int n_in,
                              void* d_out, int out_size, void* d_ws, size_t ws_size,
                              hipStream_t stream) {
  const float* img1 = (const float*)d_in[0];
  const float* img2 = (const float*)d_in[1];
  float* out = (float*)d_out;

  char* p = (char*)d_ws;
  auto alloc = [&](size_t bytes) { char* r = p; p += (bytes + 255) & ~(size_t)255; return r; };
  int*   offs     = (int*)alloc(1024 * 4);
  int*   counts   = (int*)alloc(2 * 4);
  float* sel_val  = (float*)alloc(2 * KPT * 4);
  int*   sel_idx  = (int*)alloc(2 * KPT * 4);
  float* aa       = (float*)alloc(513 * 4);
  float* bb       = (float*)alloc(513 * 4);
  float* a2       = (float*)alloc(2 * KPT * 4);
  float* smooth   = (float*)alloc((size_t)2 * HW * 4);
  float* cand_val = (float*)alloc((size_t)2 * CAP * 4);
  int*   cand_idx = (int*)alloc((size_t)2 * CAP * 4);
  int*   rank_arr = (int*)alloc((size_t)2 * CAP * 4);
  float* desc     = (float*)alloc((size_t)2 * KPT * DESC * 4);
  float* K        = (float*)alloc((size_t)513 * 513 * 4);
  float* Kt       = (float*)alloc((size_t)513 * 513 * 4);

  init_offsets_kernel<<<1, 256, 0, stream>>>(offs);
  init_misc_kernel<<<64, 256, 0, stream>>>(counts, sel_val, sel_idx, aa, bb, rank_arr, K, Kt);
  det_nms_kernel<<<dim3(IMW / FTW, IMH / FTH, 2), 256, 0, stream>>>(img1, img2, smooth,
                                                                    cand_val, cand_idx, counts);
  rank_partial_kernel<<<dim3(CAP / 256, CAP / 256, 2), 256, 0, stream>>>(cand_val, cand_idx, counts, rank_arr);
  scatter_topk_kernel<<<dim3(CAP / 256, 2), 256, 0, stream>>>(cand_val, cand_idx, counts, rank_arr, sel_val, sel_idx);
  kp_desc_kernel<<<1024, 64, 0, stream>>>(sel_val, sel_idx, smooth, offs, desc, a2, out);
  similarity_tiled_kernel<<<dim3(16, 16), 256, 0, stream>>>(desc, a2, K, Kt);
  for (int it = 0; it < 20; ++it) {
    matvec_div_kernel<<<513, 64, 0, stream>>>(K, bb, aa);   // a = mu / (K b)
    matvec_div_kernel<<<513, 64, 0, stream>>>(Kt, aa, bb);  // b = nu / (K^T a)
  }
  probs_kernel<<<(513 * 513 + 255) / 256, 256, 0, stream>>>(K, aa, bb, out + 2048);
}

// Round 12
// 282.837 us; speedup vs baseline: 2.4596x; 1.0305x over previous
//
#include <hip/hip_runtime.h>
#include <math.h>

#define IMH 480
#define IMW 640
#define HW (IMH*IMW)
#define KPT 512
#define DESC 256
#define CAP 12288
#define NMSR 3

// ---------------------------------------------------------------- BAD offsets at COMPILE TIME
// np.random.RandomState(42).uniform(-8,8,(256,4)) -> np.round (half-to-even) -> int.
// Pure constants; computed by constexpr MT19937 and emitted as __constant__ data.
// (R2's device kernel version cost a dispatch + ~5 us; this costs zero.)
struct OffsTable { int v[1024]; };

constexpr unsigned mt_temper(unsigned y) {
  y ^= (y >> 11);
  y ^= (y << 7)  & 0x9d2c5680u;
  y ^= (y << 15) & 0xefc60000u;
  y ^= (y >> 18);
  return y;
}

constexpr OffsTable make_offs() {
  OffsTable T{};
  unsigned mt[624]{};
  unsigned s = 42u;
  for (int i = 0; i < 624; ++i) { mt[i] = s; s = 1812433253u * (s ^ (s >> 30)) + (unsigned)i + 1u; }
  int mti = 624;
  unsigned draws[2048]{};
  for (int i = 0; i < 2048; ++i) {
    if (mti >= 624) {
      for (int k = 0; k < 624; ++k) {
        unsigned y = (mt[k] & 0x80000000u) | (mt[(k + 1) % 624] & 0x7fffffffu);
        unsigned v = mt[(k + 397) % 624] ^ (y >> 1);
        if (y & 1u) v ^= 0x9908b0dfu;
        mt[k] = v;
      }
      mti = 0;
    }
    draws[i] = mt_temper(mt[mti++]);
  }
  for (int i = 0; i < 1024; ++i) {
    unsigned a = draws[2 * i] >> 5, b = draws[2 * i + 1] >> 6;
    double r = ((double)a * 67108864.0 + (double)b) / 9007199254740992.0;
    double val = -8.0 + 16.0 * r;
    double f = (double)(long long)val;
    if (val < f) f -= 1.0;                 // floor
    double diff = val - f;
    double rounded;
    if (diff > 0.5) rounded = f + 1.0;
    else if (diff < 0.5) rounded = f;
    else { long long fi = (long long)f; rounded = (fi % 2 == 0) ? f : f + 1.0; }  // half->even
    T.v[i] = (int)rounded;
  }
  return T;
}

__constant__ OffsTable OFFS_TAB = make_offs();

// ---------------------------------------------------------------- init
__global__ void init_misc_kernel(int* __restrict__ counts, float* __restrict__ sel_val,
                                 int* __restrict__ sel_idx, float* __restrict__ a,
                                 float* __restrict__ b, int* __restrict__ rank_arr,
                                 float* __restrict__ K, float* __restrict__ Kt) {
  int t = blockIdx.x * blockDim.x + threadIdx.x;
  if (t < 2) counts[t] = 0;
  if (t < 2 * KPT) { sel_val[t] = 0.f; sel_idx[t] = -1; }
  if (t < 513) { a[t] = 1.f; b[t] = 1.f; }   // b=exp(v)=1 initial; a overwritten first phase
  if (t < 513) {
    // dustbin row/col of the linear-domain kernel matrix: exp(UNUSED/EPS)=exp(1)
    float e = expf(1.0f);
    K[(size_t)KPT * 513 + t] = e;  K[(size_t)t * 513 + KPT] = e;
    Kt[(size_t)KPT * 513 + t] = e; Kt[(size_t)t * 513 + KPT] = e;
  }
  for (int i = t; i < 2 * CAP; i += 16384) rank_arr[i] = 0;
}

// ---------------------------------------------------------------- fused detector + NMS
#define FTW 64
#define FTH 8
__global__ void det_nms_kernel(const float* __restrict__ img0, const float* __restrict__ img1,
                               float* __restrict__ smooth,
                               float* __restrict__ cand_val, int* __restrict__ cand_idx,
                               int* __restrict__ counts) {
  const int b = blockIdx.z;
  const int x0 = blockIdx.x * FTW;
  const int y0 = blockIdx.y * FTH;
  const float* __restrict__ img = b ? img1 : img0;
  __shared__ float im[(FTH + 10) * (FTW + 10)];   // 18 x 74 image stage (0 OOB)
  __shared__ float scs[(FTH + 6) * (FTW + 6)];    // 14 x 70 scores (-inf OOB)
  __shared__ float hm[(FTH + 6) * FTW];           // 14 x 64 horizontal 7-max
  __shared__ float lval[128];
  __shared__ int lidx[128];
  __shared__ int lcnt, gbase;
  const int tid = threadIdx.x;
  if (tid == 0) lcnt = 0;
  for (int i = tid; i < 18 * 74; i += 256) {
    int ly = i / 74, lx = i - ly * 74;
    int gy = y0 + ly - 5, gx = x0 + lx - 5;
    im[i] = (gy >= 0 && gy < IMH && gx >= 0 && gx < IMW) ? img[gy * IMW + gx] : 0.f;
  }
  __syncthreads();
  for (int i = tid; i < 14 * 70; i += 256) {
    int ly = i / 70, lx = i - ly * 70;
    int gy = y0 + ly - 3, gx = x0 + lx - 3;
    float sc;
    if (gy < 0 || gy >= IMH || gx < 0 || gx >= IMW) {
      sc = -INFINITY;                 // reference NMS pads with -inf
    } else {
      float a[5][5];
      #pragma unroll
      for (int ii = 0; ii < 5; ++ii)
        #pragma unroll
        for (int jj = 0; jj < 5; ++jj)
          a[ii][jj] = im[(ly + ii) * 74 + lx + jj];
      float sm = 0.f;
      #pragma unroll
      for (int ii = 0; ii < 5; ++ii)
        #pragma unroll
        for (int jj = 0; jj < 5; ++jj) sm += a[ii][jj];
      if (ly >= 3 && ly < 3 + FTH && lx >= 3 && lx < 3 + FTW)
        smooth[b * HW + gy * IMW + gx] = sm * (1.f / 25.f);
      float sxx = 0.f, syy = 0.f, sxy = 0.f;
      #pragma unroll
      for (int cy = -1; cy <= 1; ++cy) {
        #pragma unroll
        for (int cx = -1; cx <= 1; ++cx) {
          int yy = gy + cy, xx = gx + cx;
          if (yy < 0 || yy >= IMH || xx < 0 || xx >= IMW) continue;  // zero-pad box conv
          int iu = cy + 2, iv = cx + 2;
          float ix = (a[iu - 1][iv + 1] - a[iu - 1][iv - 1])
                   + 2.f * (a[iu][iv + 1] - a[iu][iv - 1])
                   + (a[iu + 1][iv + 1] - a[iu + 1][iv - 1]);
          float iy = (a[iu + 1][iv - 1] + 2.f * a[iu + 1][iv] + a[iu + 1][iv + 1])
                   - (a[iu - 1][iv - 1] + 2.f * a[iu - 1][iv] + a[iu - 1][iv + 1]);
          sxx += ix * ix; syy += iy * iy; sxy += ix * iy;
        }
      }
      sxx *= (1.f / 9.f); syy *= (1.f / 9.f); sxy *= (1.f / 9.f);
      float half_tr = 0.5f * (sxx + syy);
      float hd = 0.5f * (sxx - syy);
      sc = half_tr - sqrtf(hd * hd + sxy * sxy + 1e-12f);
    }
    scs[i] = sc;
  }
  __syncthreads();
  for (int i = tid; i < 14 * 64; i += 256) {
    int ly = i / 64, lx = i - ly * 64;
    const float* r = scs + ly * 70 + lx;
    float m = r[0];
    #pragma unroll
    for (int d = 1; d < 7; ++d) m = fmaxf(m, r[d]);
    hm[i] = m;
  }
  __syncthreads();
  for (int i = tid; i < FTH * FTW; i += 256) {
    int ly = i >> 6, lx = i & 63;
    float s = scs[(ly + 3) * 70 + lx + 3];
    if (s > 0.f) {
      float m = hm[ly * 64 + lx];
      #pragma unroll
      for (int d = 1; d < 7; ++d) m = fmaxf(m, hm[(ly + d) * 64 + lx]);
      if (s >= m - 1e-7f) {
        int slot = atomicAdd(&lcnt, 1);
        if (slot < 128) { lval[slot] = s; lidx[slot] = (y0 + ly) * IMW + (x0 + lx); }
      }
    }
  }
  __syncthreads();
  if (tid == 0) gbase = atomicAdd(&counts[b], min(lcnt, 128));
  __syncthreads();
  int nc = min(lcnt, 128);
  for (int i = tid; i < nc; i += 256) {
    int slot = gbase + i;
    if (slot < CAP) {
      cand_val[b * CAP + slot] = lval[i];
      cand_idx[b * CAP + slot] = lidx[i];
    }
  }
}

// ---------------------------------------------------------------- top-512: 2D-tiled rank count
__global__ void rank_partial_kernel(const float* __restrict__ cand_val,
                                    const int* __restrict__ cand_idx,
                                    const int* __restrict__ counts,
                                    int* __restrict__ rank_arr) {
  int b = blockIdx.z;
  int n = counts[b]; if (n > CAP) n = CAP;
  if ((int)(blockIdx.x * 256) >= n || (int)(blockIdx.y * 256) >= n) return;
  const float* cv = cand_val + b * CAP;
  const int* ci = cand_idx + b * CAP;
  int i = blockIdx.x * 256 + threadIdx.x;
  int j = blockIdx.y * 256 + threadIdx.x;
  __shared__ unsigned long long sk[256];
  sk[threadIdx.x] = (j < n)
      ? (((unsigned long long)__float_as_uint(cv[j]) << 32) | (0xFFFFFFFFu - (unsigned)ci[j]))
      : 0ull;
  __syncthreads();
  if (i >= n) return;
  unsigned long long ki = ((unsigned long long)__float_as_uint(cv[i]) << 32)
                        | (0xFFFFFFFFu - (unsigned)ci[i]);
  int r = 0;
  #pragma unroll 8
  for (int t = 0; t < 256; ++t) r += (sk[t] > ki) ? 1 : 0;
  atomicAdd(&rank_arr[b * CAP + i], r);
}

__global__ void scatter_topk_kernel(const float* __restrict__ cand_val,
                                    const int* __restrict__ cand_idx,
                                    const int* __restrict__ counts,
                                    const int* __restrict__ rank_arr,
                                    float* __restrict__ sel_val, int* __restrict__ sel_idx) {
  int b = blockIdx.y;
  int n = counts[b]; if (n > CAP) n = CAP;
  int i = blockIdx.x * 256 + threadIdx.x;
  if (i >= n) return;
  int r = rank_arr[b * CAP + i];
  if (r < KPT) {
    sel_val[b * KPT + r] = cand_val[b * CAP + i];
    sel_idx[b * KPT + r] = cand_idx[b * CAP + i];
  }
}

// ---------------------------------------------------------------- kp out + BAD desc + L2 norm
__global__ void kp_desc_kernel(const float* __restrict__ sel_val, const int* __restrict__ sel_idx,
                               const float* __restrict__ smooth,
                               float* __restrict__ desc, float* __restrict__ a2_out,
                               float* __restrict__ out) {
  int blk = blockIdx.x;
  int b = blk >> 9;
  int k = blk & 511;
  int lane = threadIdx.x;
  float val = sel_val[b * KPT + k];
  int idx = sel_idx[b * KPT + k];
  bool valid = (val > 0.f) && (idx >= 0);
  int y = 0, x = 0;
  if (valid) { y = idx / IMW; x = idx - y * IMW; }
  const float* sm = smooth + b * HW;
  float d[4];
  #pragma unroll
  for (int t2 = 0; t2 < 4; ++t2) {
    int pp = (lane << 2) + t2;
    int oy1 = OFFS_TAB.v[4 * pp + 0], ox1 = OFFS_TAB.v[4 * pp + 1];
    int oy2 = OFFS_TAB.v[4 * pp + 2], ox2 = OFFS_TAB.v[4 * pp + 3];
    int ya = min(max(y + oy1, 0), IMH - 1), xa = min(max(x + ox1, 0), IMW - 1);
    int yb = min(max(y + oy2, 0), IMH - 1), xb = min(max(x + ox2, 0), IMW - 1);
    float v2 = sm[ya * IMW + xa] - sm[yb * IMW + xb];
    d[t2] = valid ? v2 : 0.f;
  }
  float ss = d[0] * d[0] + d[1] * d[1] + d[2] * d[2] + d[3] * d[3];
  #pragma unroll
  for (int off = 32; off; off >>= 1) ss += __shfl_down(ss, off);
  ss = __shfl(ss, 0);
  float scale = 1.f / (sqrtf(ss) + 1e-8f);
  float* dd = desc + (size_t)(b * KPT + k) * DESC;
  #pragma unroll
  for (int t2 = 0; t2 < 4; ++t2) dd[(lane << 2) + t2] = d[t2] * scale;
  if (lane == 0) {
    a2_out[b * KPT + k] = ss * scale * scale;
    float* kp = out + b * (2 * KPT) + k * 2;
    kp[0] = valid ? (float)y : -1.f;
    kp[1] = valid ? (float)x : -1.f;
  }
}

// ---------------------------------------------------------------- similarity: LDS-tiled GEMM, 256 blocks
#define CK 64
#define APITCH 34
__global__ __launch_bounds__(256) void similarity_tiled_kernel(
    const float* __restrict__ desc, const float* __restrict__ a2,
    float* __restrict__ K, float* __restrict__ Kt) {
  __shared__ float As[CK * APITCH];   // [k][row]
  __shared__ float Bs[CK * APITCH];   // [k][col]
  __shared__ float T[32 * 33];        // output tile for coalesced writes
  const int tid = threadIdx.x;
  const int tx = tid & 15;        // col-pair index
  const int ty = tid >> 4;        // row-pair index
  const int row0 = blockIdx.y * 32;
  const int col0 = blockIdx.x * 32;
  float acc[2][2] = {};
  for (int kc = 0; kc < DESC; kc += CK) {
    for (int i = tid; i < 32 * CK; i += 256) {
      int c = i & (CK - 1), r = i >> 6;   // consecutive lanes -> consecutive c: coalesced
      As[c * APITCH + r] = desc[(size_t)(row0 + r) * DESC + kc + c];
      Bs[c * APITCH + r] = desc[(size_t)(KPT + col0 + r) * DESC + kc + c];
    }
    __syncthreads();
    #pragma unroll 16
    for (int kk = 0; kk < CK; ++kk) {
      const float2 av = *(const float2*)&As[kk * APITCH + ty * 2];
      const float2 bv = *(const float2*)&Bs[kk * APITCH + tx * 2];
      acc[0][0] += av.x * bv.x; acc[0][1] += av.x * bv.y;
      acc[1][0] += av.y * bv.x; acc[1][1] += av.y * bv.y;
    }
    __syncthreads();
  }
  float a2k[2], b2l[2];
  #pragma unroll
  for (int i = 0; i < 2; ++i) {
    a2k[i] = a2[row0 + ty * 2 + i];
    b2l[i] = a2[KPT + col0 + tx * 2 + i];
  }
  #pragma unroll
  for (int i = 0; i < 2; ++i)
    #pragma unroll
    for (int j = 0; j < 2; ++j) {
      float sq = fmaxf(a2k[i] + b2l[j] - 2.f * acc[i][j], 0.f);
      T[(ty * 2 + i) * 33 + tx * 2 + j] = expf(-sqrtf(sq + 1e-12f));
    }
  __syncthreads();
  for (int i = tid; i < 1024; i += 256) {
    int r = i >> 5, c = i & 31;
    K[(size_t)(row0 + r) * 513 + col0 + c] = T[r * 33 + c];
  }
  for (int i = tid; i < 1024; i += 256) {
    int r = i & 31, c = i >> 5;
    Kt[(size_t)(col0 + c) * 513 + row0 + r] = T[r * 33 + c];
  }
}

// ---------------------------------------------------------------- sinkhorn, linear domain, multi-dispatch
// a = mu / (K b);  b = nu / (K^T a);  probs = K * a * b * 1024.
// Dispatch boundary IS the grid barrier (~2 us, graph-amortized) — every
// hand-rolled cross-XCD barrier measured 8-12 us/sync (R4/R5/R6).
__global__ void matvec_div_kernel(const float* __restrict__ M, const float* __restrict__ x,
                                  float* __restrict__ y) {
  const int r = blockIdx.x;          // 0..512
  const int lane = threadIdx.x;      // one wave
  const float* row = M + (size_t)r * 513;
  float s = 0.f;
  for (int i = lane; i < 513; i += 64) s += row[i] * x[i];
  #pragma unroll
  for (int off = 32; off; off >>= 1) s += __shfl_xor(s, off);
  if (lane == 0) {
    const float mu = (r == KPT) ? 0.5f : (1.0f / 1024.0f);
    y[r] = mu / s;
  }
}

__global__ void probs_kernel(const float* __restrict__ K, const float* __restrict__ a,
                             const float* __restrict__ b, float* __restrict__ out) {
  int t = blockIdx.x * blockDim.x + threadIdx.x;
  if (t >= 513 * 513) return;
  int k = t / 513;
  int l = t - k * 513;
  out[t] = K[t] * (a[k] * 1024.f) * b[l];
}

// ---------------------------------------------------------------- launch
extern "C" void kernel_launch(void* const* d_in, const int* in_sizes, int n_in,
                              void* d_out, int out_size, void* d_ws, size_t ws_size,
                              hipStream_t stream) {
  const float* img1 = (const float*)d_in[0];
  const float* img2 = (const float*)d_in[1];
  float* out = (float*)d_out;

  char* p = (char*)d_ws;
  auto alloc = [&](size_t bytes) { char* r = p; p += (bytes + 255) & ~(size_t)255; return r; };
  int*   counts   = (int*)alloc(2 * 4);
  float* sel_val  = (float*)alloc(2 * KPT * 4);
  int*   sel_idx  = (int*)alloc(2 * KPT * 4);
  float* aa       = (float*)alloc(513 * 4);
  float* bb       = (float*)alloc(513 * 4);
  float* a2       = (float*)alloc(2 * KPT * 4);
  float* smooth   = (float*)alloc((size_t)2 * HW * 4);
  float* cand_val = (float*)alloc((size_t)2 * CAP * 4);
  int*   cand_idx = (int*)alloc((size_t)2 * CAP * 4);
  int*   rank_arr = (int*)alloc((size_t)2 * CAP * 4);
  float* desc     = (float*)alloc((size_t)2 * KPT * DESC * 4);
  float* K        = (float*)alloc((size_t)513 * 513 * 4);
  float* Kt       = (float*)alloc((size_t)513 * 513 * 4);

  init_misc_kernel<<<64, 256, 0, stream>>>(counts, sel_val, sel_idx, aa, bb, rank_arr, K, Kt);
  det_nms_kernel<<<dim3(IMW / FTW, IMH / FTH, 2), 256, 0, stream>>>(img1, img2, smooth,
                                                                    cand_val, cand_idx, counts);
  rank_partial_kernel<<<dim3(CAP / 256, CAP / 256, 2), 256, 0, stream>>>(cand_val, cand_idx, counts, rank_arr);
  scatter_topk_kernel<<<dim3(CAP / 256, 2), 256, 0, stream>>>(cand_val, cand_idx, counts, rank_arr, sel_val, sel_idx);
  kp_desc_kernel<<<1024, 64, 0, stream>>>(sel_val, sel_idx, smooth, desc, a2, out);
  similarity_tiled_kernel<<<dim3(16, 16), 256, 0, stream>>>(desc, a2, K, Kt);
  for (int it = 0; it < 20; ++it) {
    matvec_div_kernel<<<513, 64, 0, stream>>>(K, bb, aa);   // a = mu / (K b)
    matvec_div_kernel<<<513, 64, 0, stream>>>(Kt, aa, bb);  // b = nu / (K^T a)
  }
  probs_kernel<<<(513 * 513 + 255) / 256, 256, 0, stream>>>(K, aa, bb, out + 2048);
}

// Round 13
// 278.243 us; speedup vs baseline: 2.5003x; 1.0165x over previous
//
#include <hip/hip_runtime.h>
#include <math.h>

#define IMH 480
#define IMW 640
#define HW (IMH*IMW)
#define KPT 512
#define DESC 256
#define CAP 12288
#define NMSR 3

// ---------------------------------------------------------------- BAD offsets at COMPILE TIME
// np.random.RandomState(42).uniform(-8,8,(256,4)) -> np.round (half-to-even) -> int.
struct OffsTable { int v[1024]; };

constexpr unsigned mt_temper(unsigned y) {
  y ^= (y >> 11);
  y ^= (y << 7)  & 0x9d2c5680u;
  y ^= (y << 15) & 0xefc60000u;
  y ^= (y >> 18);
  return y;
}

constexpr OffsTable make_offs() {
  OffsTable T{};
  unsigned mt[624]{};
  unsigned s = 42u;
  for (int i = 0; i < 624; ++i) { mt[i] = s; s = 1812433253u * (s ^ (s >> 30)) + (unsigned)i + 1u; }
  int mti = 624;
  unsigned draws[2048]{};
  for (int i = 0; i < 2048; ++i) {
    if (mti >= 624) {
      for (int k = 0; k < 624; ++k) {
        unsigned y = (mt[k] & 0x80000000u) | (mt[(k + 1) % 624] & 0x7fffffffu);
        unsigned v = mt[(k + 397) % 624] ^ (y >> 1);
        if (y & 1u) v ^= 0x9908b0dfu;
        mt[k] = v;
      }
      mti = 0;
    }
    draws[i] = mt_temper(mt[mti++]);
  }
  for (int i = 0; i < 1024; ++i) {
    unsigned a = draws[2 * i] >> 5, b = draws[2 * i + 1] >> 6;
    double r = ((double)a * 67108864.0 + (double)b) / 9007199254740992.0;
    double val = -8.0 + 16.0 * r;
    double f = (double)(long long)val;
    if (val < f) f -= 1.0;                 // floor
    double diff = val - f;
    double rounded;
    if (diff > 0.5) rounded = f + 1.0;
    else if (diff < 0.5) rounded = f;
    else { long long fi = (long long)f; rounded = (fi % 2 == 0) ? f : f + 1.0; }  // half->even
    T.v[i] = (int)rounded;
  }
  return T;
}

__constant__ OffsTable OFFS_TAB = make_offs();

// ---------------------------------------------------------------- init
__global__ void init_misc_kernel(int* __restrict__ counts, float* __restrict__ sel_val,
                                 int* __restrict__ sel_idx, float* __restrict__ a,
                                 float* __restrict__ b, int* __restrict__ rank_arr,
                                 float* __restrict__ K, float* __restrict__ Kt) {
  int t = blockIdx.x * blockDim.x + threadIdx.x;
  if (t < 2) counts[t] = 0;
  if (t < 2 * KPT) { sel_val[t] = 0.f; sel_idx[t] = -1; }
  if (t < 513) { a[t] = 1.f; b[t] = 1.f; }   // b=exp(v)=1 initial; a overwritten first phase
  if (t < 513) {
    // dustbin row/col of the linear-domain kernel matrix: exp(UNUSED/EPS)=exp(1)
    float e = expf(1.0f);
    K[(size_t)KPT * 513 + t] = e;  K[(size_t)t * 513 + KPT] = e;
    Kt[(size_t)KPT * 513 + t] = e; Kt[(size_t)t * 513 + KPT] = e;
  }
  for (int i = t; i < 2 * CAP; i += 16384) rank_arr[i] = 0;
}

// ---------------------------------------------------------------- fused detector + NMS
#define FTW 64
#define FTH 8
__global__ void det_nms_kernel(const float* __restrict__ img0, const float* __restrict__ img1,
                               float* __restrict__ smooth,
                               float* __restrict__ cand_val, int* __restrict__ cand_idx,
                               int* __restrict__ counts) {
  const int b = blockIdx.z;
  const int x0 = blockIdx.x * FTW;
  const int y0 = blockIdx.y * FTH;
  const float* __restrict__ img = b ? img1 : img0;
  __shared__ float im[(FTH + 10) * (FTW + 10)];   // 18 x 74 image stage (0 OOB)
  __shared__ float scs[(FTH + 6) * (FTW + 6)];    // 14 x 70 scores (-inf OOB)
  __shared__ float hm[(FTH + 6) * FTW];           // 14 x 64 horizontal 7-max
  __shared__ float lval[128];
  __shared__ int lidx[128];
  __shared__ int lcnt, gbase;
  const int tid = threadIdx.x;
  if (tid == 0) lcnt = 0;
  for (int i = tid; i < 18 * 74; i += 256) {
    int ly = i / 74, lx = i - ly * 74;
    int gy = y0 + ly - 5, gx = x0 + lx - 5;
    im[i] = (gy >= 0 && gy < IMH && gx >= 0 && gx < IMW) ? img[gy * IMW + gx] : 0.f;
  }
  __syncthreads();
  for (int i = tid; i < 14 * 70; i += 256) {
    int ly = i / 70, lx = i - ly * 70;
    int gy = y0 + ly - 3, gx = x0 + lx - 3;
    float sc;
    if (gy < 0 || gy >= IMH || gx < 0 || gx >= IMW) {
      sc = -INFINITY;                 // reference NMS pads with -inf
    } else {
      float a[5][5];
      #pragma unroll
      for (int ii = 0; ii < 5; ++ii)
        #pragma unroll
        for (int jj = 0; jj < 5; ++jj)
          a[ii][jj] = im[(ly + ii) * 74 + lx + jj];
      float sm = 0.f;
      #pragma unroll
      for (int ii = 0; ii < 5; ++ii)
        #pragma unroll
        for (int jj = 0; jj < 5; ++jj) sm += a[ii][jj];
      if (ly >= 3 && ly < 3 + FTH && lx >= 3 && lx < 3 + FTW)
        smooth[b * HW + gy * IMW + gx] = sm * (1.f / 25.f);
      float sxx = 0.f, syy = 0.f, sxy = 0.f;
      #pragma unroll
      for (int cy = -1; cy <= 1; ++cy) {
        #pragma unroll
        for (int cx = -1; cx <= 1; ++cx) {
          int yy = gy + cy, xx = gx + cx;
          if (yy < 0 || yy >= IMH || xx < 0 || xx >= IMW) continue;  // zero-pad box conv
          int iu = cy + 2, iv = cx + 2;
          float ix = (a[iu - 1][iv + 1] - a[iu - 1][iv - 1])
                   + 2.f * (a[iu][iv + 1] - a[iu][iv - 1])
                   + (a[iu + 1][iv + 1] - a[iu + 1][iv - 1]);
          float iy = (a[iu + 1][iv - 1] + 2.f * a[iu + 1][iv] + a[iu + 1][iv + 1])
                   - (a[iu - 1][iv - 1] + 2.f * a[iu - 1][iv] + a[iu - 1][iv + 1]);
          sxx += ix * ix; syy += iy * iy; sxy += ix * iy;
        }
      }
      sxx *= (1.f / 9.f); syy *= (1.f / 9.f); sxy *= (1.f / 9.f);
      float half_tr = 0.5f * (sxx + syy);
      float hd = 0.5f * (sxx - syy);
      sc = half_tr - sqrtf(hd * hd + sxy * sxy + 1e-12f);
    }
    scs[i] = sc;
  }
  __syncthreads();
  for (int i = tid; i < 14 * 64; i += 256) {
    int ly = i / 64, lx = i - ly * 64;
    const float* r = scs + ly * 70 + lx;
    float m = r[0];
    #pragma unroll
    for (int d = 1; d < 7; ++d) m = fmaxf(m, r[d]);
    hm[i] = m;
  }
  __syncthreads();
  for (int i = tid; i < FTH * FTW; i += 256) {
    int ly = i >> 6, lx = i & 63;
    float s = scs[(ly + 3) * 70 + lx + 3];
    if (s > 0.f) {
      float m = hm[ly * 64 + lx];
      #pragma unroll
      for (int d = 1; d < 7; ++d) m = fmaxf(m, hm[(ly + d) * 64 + lx]);
      if (s >= m - 1e-7f) {
        int slot = atomicAdd(&lcnt, 1);
        if (slot < 128) { lval[slot] = s; lidx[slot] = (y0 + ly) * IMW + (x0 + lx); }
      }
    }
  }
  __syncthreads();
  if (tid == 0) gbase = atomicAdd(&counts[b], min(lcnt, 128));
  __syncthreads();
  int nc = min(lcnt, 128);
  for (int i = tid; i < nc; i += 256) {
    int slot = gbase + i;
    if (slot < CAP) {
      cand_val[b * CAP + slot] = lval[i];
      cand_idx[b * CAP + slot] = lidx[i];
    }
  }
}

// ---------------------------------------------------------------- top-512: 2D-tiled rank count
__global__ void rank_partial_kernel(const float* __restrict__ cand_val,
                                    const int* __restrict__ cand_idx,
                                    const int* __restrict__ counts,
                                    int* __restrict__ rank_arr) {
  int b = blockIdx.z;
  int n = counts[b]; if (n > CAP) n = CAP;
  if ((int)(blockIdx.x * 256) >= n || (int)(blockIdx.y * 256) >= n) return;
  const float* cv = cand_val + b * CAP;
  const int* ci = cand_idx + b * CAP;
  int i = blockIdx.x * 256 + threadIdx.x;
  int j = blockIdx.y * 256 + threadIdx.x;
  __shared__ unsigned long long sk[256];
  sk[threadIdx.x] = (j < n)
      ? (((unsigned long long)__float_as_uint(cv[j]) << 32) | (0xFFFFFFFFu - (unsigned)ci[j]))
      : 0ull;
  __syncthreads();
  if (i >= n) return;
  unsigned long long ki = ((unsigned long long)__float_as_uint(cv[i]) << 32)
                        | (0xFFFFFFFFu - (unsigned)ci[i]);
  int r = 0;
  #pragma unroll 8
  for (int t = 0; t < 256; ++t) r += (sk[t] > ki) ? 1 : 0;
  atomicAdd(&rank_arr[b * CAP + i], r);
}

__global__ void scatter_topk_kernel(const float* __restrict__ cand_val,
                                    const int* __restrict__ cand_idx,
                                    const int* __restrict__ counts,
                                    const int* __restrict__ rank_arr,
                                    float* __restrict__ sel_val, int* __restrict__ sel_idx) {
  int b = blockIdx.y;
  int n = counts[b]; if (n > CAP) n = CAP;
  int i = blockIdx.x * 256 + threadIdx.x;
  if (i >= n) return;
  int r = rank_arr[b * CAP + i];
  if (r < KPT) {
    sel_val[b * KPT + r] = cand_val[b * CAP + i];
    sel_idx[b * KPT + r] = cand_idx[b * CAP + i];
  }
}

// ---------------------------------------------------------------- kp out + BAD desc + L2 norm
__global__ void kp_desc_kernel(const float* __restrict__ sel_val, const int* __restrict__ sel_idx,
                               const float* __restrict__ smooth,
                               float* __restrict__ desc, float* __restrict__ a2_out,
                               float* __restrict__ out) {
  int blk = blockIdx.x;
  int b = blk >> 9;
  int k = blk & 511;
  int lane = threadIdx.x;
  float val = sel_val[b * KPT + k];
  int idx = sel_idx[b * KPT + k];
  bool valid = (val > 0.f) && (idx >= 0);
  int y = 0, x = 0;
  if (valid) { y = idx / IMW; x = idx - y * IMW; }
  const float* sm = smooth + b * HW;
  float d[4];
  #pragma unroll
  for (int t2 = 0; t2 < 4; ++t2) {
    int pp = (lane << 2) + t2;
    int oy1 = OFFS_TAB.v[4 * pp + 0], ox1 = OFFS_TAB.v[4 * pp + 1];
    int oy2 = OFFS_TAB.v[4 * pp + 2], ox2 = OFFS_TAB.v[4 * pp + 3];
    int ya = min(max(y + oy1, 0), IMH - 1), xa = min(max(x + ox1, 0), IMW - 1);
    int yb = min(max(y + oy2, 0), IMH - 1), xb = min(max(x + ox2, 0), IMW - 1);
    float v2 = sm[ya * IMW + xa] - sm[yb * IMW + xb];
    d[t2] = valid ? v2 : 0.f;
  }
  float ss = d[0] * d[0] + d[1] * d[1] + d[2] * d[2] + d[3] * d[3];
  #pragma unroll
  for (int off = 32; off; off >>= 1) ss += __shfl_down(ss, off);
  ss = __shfl(ss, 0);
  float scale = 1.f / (sqrtf(ss) + 1e-8f);
  float* dd = desc + (size_t)(b * KPT + k) * DESC;
  #pragma unroll
  for (int t2 = 0; t2 < 4; ++t2) dd[(lane << 2) + t2] = d[t2] * scale;
  if (lane == 0) {
    a2_out[b * KPT + k] = ss * scale * scale;
    float* kp = out + b * (2 * KPT) + k * 2;
    kp[0] = valid ? (float)y : -1.f;
    kp[1] = valid ? (float)x : -1.f;
  }
}

// ---------------------------------------------------------------- similarity: LDS-tiled GEMM, 512 blocks
// 32x16 tile/block, 128 threads, 2x2 regs/thread. Grid 32x16 = 512 blocks ->
// 2 blocks/CU co-resident (R10's grid-256 = 1 block/CU left every barrier/
// staging stall exposed — that was the residual ~26 us). CK=128: 2 chunks,
// half the barriers. Accumulation strictly k-ascending -> per-element dot
// order identical to R11 (bit-identical interior).
#define CK 128
#define APITCH 34
#define BPITCH 18
__global__ __launch_bounds__(128) void similarity_tiled_kernel(
    const float* __restrict__ desc, const float* __restrict__ a2,
    float* __restrict__ K, float* __restrict__ Kt) {
  __shared__ float As[CK * APITCH];   // [k][row], 32 rows
  __shared__ float Bs[CK * BPITCH];   // [k][col], 16 cols
  __shared__ float T[32 * 17];        // output tile for coalesced writes
  const int tid = threadIdx.x;
  const int tx = tid & 7;         // col-pair index (16 cols)
  const int ty = tid >> 3;        // row-pair index (32 rows)
  const int row0 = blockIdx.y * 32;
  const int col0 = blockIdx.x * 16;
  float acc[2][2] = {};
  for (int kc = 0; kc < DESC; kc += CK) {
    for (int i = tid; i < 32 * CK; i += 128) {
      int c = i & (CK - 1), r = i >> 7;   // consecutive lanes -> consecutive c: coalesced
      As[c * APITCH + r] = desc[(size_t)(row0 + r) * DESC + kc + c];
    }
    for (int i = tid; i < 16 * CK; i += 128) {
      int c = i & (CK - 1), r = i >> 7;
      Bs[c * BPITCH + r] = desc[(size_t)(KPT + col0 + r) * DESC + kc + c];
    }
    __syncthreads();
    #pragma unroll 16
    for (int kk = 0; kk < CK; ++kk) {
      const float2 av = *(const float2*)&As[kk * APITCH + ty * 2];
      const float2 bv = *(const float2*)&Bs[kk * BPITCH + tx * 2];
      acc[0][0] += av.x * bv.x; acc[0][1] += av.x * bv.y;
      acc[1][0] += av.y * bv.x; acc[1][1] += av.y * bv.y;
    }
    __syncthreads();
  }
  float a2k[2], b2l[2];
  #pragma unroll
  for (int i = 0; i < 2; ++i) {
    a2k[i] = a2[row0 + ty * 2 + i];
    b2l[i] = a2[KPT + col0 + tx * 2 + i];
  }
  #pragma unroll
  for (int i = 0; i < 2; ++i)
    #pragma unroll
    for (int j = 0; j < 2; ++j) {
      float sq = fmaxf(a2k[i] + b2l[j] - 2.f * acc[i][j], 0.f);
      T[(ty * 2 + i) * 17 + tx * 2 + j] = expf(-sqrtf(sq + 1e-12f));
    }
  __syncthreads();
  for (int i = tid; i < 512; i += 128) {
    int r = i >> 4, c = i & 15;
    K[(size_t)(row0 + r) * 513 + col0 + c] = T[r * 17 + c];
  }
  for (int i = tid; i < 512; i += 128) {
    int r = i & 31, c = i >> 5;
    Kt[(size_t)(col0 + c) * 513 + row0 + r] = T[r * 17 + c];
  }
}

// ---------------------------------------------------------------- sinkhorn, linear domain, multi-dispatch
// a = mu / (K b);  b = nu / (K^T a);  probs = K * a * b * 1024.
// Dispatch boundary IS the grid barrier (~2 us, graph-amortized) — every
// hand-rolled cross-XCD barrier measured 8-12 us/sync (R4/R5/R6).
__global__ void matvec_div_kernel(const float* __restrict__ M, const float* __restrict__ x,
                                  float* __restrict__ y) {
  const int r = blockIdx.x;          // 0..512
  const int lane = threadIdx.x;      // one wave
  const float* row = M + (size_t)r * 513;
  float s = 0.f;
  for (int i = lane; i < 513; i += 64) s += row[i] * x[i];
  #pragma unroll
  for (int off = 32; off; off >>= 1) s += __shfl_xor(s, off);
  if (lane == 0) {
    const float mu = (r == KPT) ? 0.5f : (1.0f / 1024.0f);
    y[r] = mu / s;
  }
}

__global__ void probs_kernel(const float* __restrict__ K, const float* __restrict__ a,
                             const float* __restrict__ b, float* __restrict__ out) {
  int t = blockIdx.x * blockDim.x + threadIdx.x;
  if (t >= 513 * 513) return;
  int k = t / 513;
  int l = t - k * 513;
  out[t] = K[t] * (a[k] * 1024.f) * b[l];
}

// ---------------------------------------------------------------- launch
extern "C" void kernel_launch(void* const* d_in, const int* in_sizes, int n_in,
                              void* d_out, int out_size, void* d_ws, size_t ws_size,
                              hipStream_t stream) {
  const float* img1 = (const float*)d_in[0];
  const float* img2 = (const float*)d_in[1];
  float* out = (float*)d_out;

  char* p = (char*)d_ws;
  auto alloc = [&](size_t bytes) { char* r = p; p += (bytes + 255) & ~(size_t)255; return r; };
  int*   counts   = (int*)alloc(2 * 4);
  float* sel_val  = (float*)alloc(2 * KPT * 4);
  int*   sel_idx  = (int*)alloc(2 * KPT * 4);
  float* aa       = (float*)alloc(513 * 4);
  float* bb       = (float*)alloc(513 * 4);
  float* a2       = (float*)alloc(2 * KPT * 4);
  float* smooth   = (float*)alloc((size_t)2 * HW * 4);
  float* cand_val = (float*)alloc((size_t)2 * CAP * 4);
  int*   cand_idx = (int*)alloc((size_t)2 * CAP * 4);
  int*   rank_arr = (int*)alloc((size_t)2 * CAP * 4);
  float* desc     = (float*)alloc((size_t)2 * KPT * DESC * 4);
  float* K        = (float*)alloc((size_t)513 * 513 * 4);
  float* Kt       = (float*)alloc((size_t)513 * 513 * 4);

  init_misc_kernel<<<64, 256, 0, stream>>>(counts, sel_val, sel_idx, aa, bb, rank_arr, K, Kt);
  det_nms_kernel<<<dim3(IMW / FTW, IMH / FTH, 2), 256, 0, stream>>>(img1, img2, smooth,
                                                                    cand_val, cand_idx, counts);
  rank_partial_kernel<<<dim3(CAP / 256, CAP / 256, 2), 256, 0, stream>>>(cand_val, cand_idx, counts, rank_arr);
  scatter_topk_kernel<<<dim3(CAP / 256, 2), 256, 0, stream>>>(cand_val, cand_idx, counts, rank_arr, sel_val, sel_idx);
  kp_desc_kernel<<<1024, 64, 0, stream>>>(sel_val, sel_idx, smooth, desc, a2, out);
  similarity_tiled_kernel<<<dim3(32, 16), 128, 0, stream>>>(desc, a2, K, Kt);
  for (int it = 0; it < 20; ++it) {
    matvec_div_kernel<<<513, 64, 0, stream>>>(K, bb, aa);   // a = mu / (K b)
    matvec_div_kernel<<<513, 64, 0, stream>>>(Kt, aa, bb);  // b = nu / (K^T a)
  }
  probs_kernel<<<(513 * 513 + 255) / 256, 256, 0, stream>>>(K, aa, bb, out + 2048);
}